// Round 1
// 201.083 us; speedup vs baseline: 1.0930x; 1.0930x over previous
//
#include <hip/hip_runtime.h>
#include <hip/hip_bf16.h>
#include <math.h>

#define SS 2048
#define HH 1024
#define NHH 16
#define HDD 64
#define BH 32
#define MM 4096

typedef unsigned short u16;
using bf16x8 = __attribute__((ext_vector_type(8))) short;
using floatx4 = __attribute__((ext_vector_type(4))) float;

__device__ __forceinline__ u16 f2bf(float f) {
  unsigned u = __float_as_uint(f);
  u += 0x7fffu + ((u >> 16) & 1u);
  return (u16)(u >> 16);
}
__device__ __forceinline__ unsigned pk_bf16(float a, float b) {
  union { __hip_bfloat162 h2; unsigned u; } c;
  c.h2 = __float22bfloat162_rn(float2{a, b});
  return c.u;
}
__device__ __forceinline__ void gload_lds16(const u16* g, u16* l) {
  __builtin_amdgcn_global_load_lds(
      (const __attribute__((address_space(1))) void*)g,
      (__attribute__((address_space(3))) void*)l, 16, 0, 0);
}

// ---------------------------------------------------------------------------
// fp32 -> bf16 conversion (hs + 4 weights) + RoPE cos/sin table.
// ---------------------------------------------------------------------------
__global__ __launch_bounds__(256) void convert_bf(
    const float* __restrict__ hs, const float* __restrict__ wq,
    const float* __restrict__ wk, const float* __restrict__ wv,
    const float* __restrict__ wo, const int* __restrict__ pos,
    u16* __restrict__ hs_b, u16* __restrict__ wq_b, u16* __restrict__ wk_b,
    u16* __restrict__ wv_b, u16* __restrict__ wo_b,
    float2* __restrict__ tab) {
  int g = blockIdx.x * 256 + threadIdx.x;
  if (g < 2097152) {
    const float* src;
    u16* dst;
    int off;
    if (g < 1048576) {
      src = hs; dst = hs_b; off = g;
    } else {
      int t = g - 1048576;
      int w = t >> 18;
      off = t & 262143;
      src = (w == 0) ? wq : (w == 1) ? wk : (w == 2) ? wv : wo;
      dst = (w == 0) ? wq_b : (w == 1) ? wk_b : (w == 2) ? wv_b : wo_b;
    }
    float4 v = ((const float4*)src)[off];
    ushort4 o = make_ushort4(f2bf(v.x), f2bf(v.y), f2bf(v.z), f2bf(v.w));
    ((ushort4*)dst)[off] = o;
  } else {
    int idx = g - 2097152;  // 0..65535
    int s = idx >> 5, j = idx & 31;
    float p = (float)pos[s];
    const float c0 = 13.287712379549449f / 32.0f;  // log2(10000)/32
    float f = p * exp2f(-(float)j * c0);
    float sn, cs;
    sincosf(f, &sn, &cs);
    tab[idx] = float2{cs, sn};
  }
}

// ---------------------------------------------------------------------------
// QKV MFMA GEMM: 128x128 tile, BK=32, global_load_lds w16, XOR swizzle.
// grid.x spans Wq|Wk|Wv; Q/K get table RoPE in the epilogue (Q pre-scaled by
// (1/sqrt(HD))*log2e), bf16 head-major out; V written transposed Vt[bh][d][s].
// ---------------------------------------------------------------------------
__global__ __launch_bounds__(256) void mfma_gemm_qkv(
    const u16* __restrict__ X, const u16* __restrict__ W0,
    const u16* __restrict__ W1, const u16* __restrict__ W2,
    const float* __restrict__ b0, const float* __restrict__ b1,
    const float* __restrict__ b2, const float2* __restrict__ tab,
    u16* __restrict__ O0, u16* __restrict__ O1, u16* __restrict__ O2) {
  __shared__ __align__(16) u16 As[128 * 32];
  __shared__ __align__(16) u16 Bs[128 * 32];
  const int tid = threadIdx.x;
  const int lane = tid & 63;
  const int wvu = __builtin_amdgcn_readfirstlane(tid >> 6);
  const int l15 = lane & 15;
  const int quad = lane >> 4;
  const int wm = wvu >> 1, wn = wvu & 1;
  const int m0 = blockIdx.y * 128;
  const int n0g = blockIdx.x * 128;
  const int lr = lane >> 2;
  const int lc = lane & 3;

  int wsel = n0g >> 10;
  int n0 = n0g & 1023;
  const u16* Wsel = (wsel == 1) ? W1 : (wsel == 2) ? W2 : W0;
  const float* bsel = (wsel == 1) ? b1 : (wsel == 2) ? b2 : b0;
  u16* Osel = (wsel == 1) ? O1 : (wsel == 2) ? O2 : O0;

  floatx4 acc[4][4];
#pragma unroll
  for (int i = 0; i < 4; ++i)
#pragma unroll
    for (int j = 0; j < 4; ++j) acc[i][j] = (floatx4){0.f, 0.f, 0.f, 0.f};

  const int scol = (lc ^ ((lr >> 1) & 3)) * 8;
  const int fsw = ((l15 >> 1) & 3);

  for (int k0 = 0; k0 < HH; k0 += 32) {
#pragma unroll
    for (int u = 0; u < 2; ++u) {
      int r = u * 64 + wvu * 16 + lr;
      gload_lds16(&X[(size_t)(m0 + r) * HH + k0 + scol],
                  &As[(u * 64 + wvu * 16) * 32]);
      gload_lds16(&Wsel[(size_t)(n0 + r) * HH + k0 + scol],
                  &Bs[(u * 64 + wvu * 16) * 32]);
    }
    __syncthreads();
    bf16x8 af[4], bfr[4];
#pragma unroll
    for (int mb = 0; mb < 4; ++mb)
      af[mb] = *(const bf16x8*)&As[(wm * 64 + mb * 16 + l15) * 32 +
                                   ((quad ^ fsw) * 8)];
#pragma unroll
    for (int nb = 0; nb < 4; ++nb)
      bfr[nb] = *(const bf16x8*)&Bs[(wn * 64 + nb * 16 + l15) * 32 +
                                    ((quad ^ fsw) * 8)];
#pragma unroll
    for (int mb = 0; mb < 4; ++mb)
#pragma unroll
      for (int nb = 0; nb < 4; ++nb)
        acc[mb][nb] = __builtin_amdgcn_mfma_f32_16x16x32_bf16(
            af[mb], bfr[nb], acc[mb][nb], 0, 0, 0);
    __syncthreads();
  }

  if (wsel < 2) {
    const float qs = (wsel == 0) ? 0.125f * 1.44269504088896f : 1.0f;
    const int colb = n0 + wn * 64;
    const int h = colb >> 6;
    const float bias0 = bsel[colb + l15];
    const float bias1 = bsel[colb + 16 + l15];
    const float bias2 = bsel[colb + 32 + l15];
    const float bias3 = bsel[colb + 48 + l15];
#pragma unroll
    for (int mb = 0; mb < 4; ++mb)
#pragma unroll
      for (int r = 0; r < 4; ++r) {
        int m = m0 + wm * 64 + mb * 16 + quad * 4 + r;
        int b = m >> 11, s = m & (SS - 1);
        float2 t0 = tab[s * 32 + l15];
        float2 t1 = tab[s * 32 + 16 + l15];
        size_t obase = ((size_t)(b * NHH + h) * SS + s) * HDD;
        float x1 = acc[mb][0][r] + bias0;
        float x2 = acc[mb][2][r] + bias2;
        Osel[obase + l15] = f2bf((x1 * t0.x - x2 * t0.y) * qs);
        Osel[obase + 32 + l15] = f2bf((x2 * t0.x + x1 * t0.y) * qs);
        float y1 = acc[mb][1][r] + bias1;
        float y2 = acc[mb][3][r] + bias3;
        Osel[obase + 16 + l15] = f2bf((y1 * t1.x - y2 * t1.y) * qs);
        Osel[obase + 48 + l15] = f2bf((y2 * t1.x + y1 * t1.y) * qs);
      }
  } else {
#pragma unroll
    for (int nb = 0; nb < 4; ++nb) {
      int col = n0 + wn * 64 + nb * 16 + l15;
      int h = col >> 6, d = col & 63;
      float bias = bsel[col];
#pragma unroll
      for (int mb = 0; mb < 4; ++mb) {
        int m = m0 + wm * 64 + mb * 16 + quad * 4;
        int b = m >> 11, s = m & (SS - 1);
        uint2 w2;
        w2.x = pk_bf16(acc[mb][nb][0] + bias, acc[mb][nb][1] + bias);
        w2.y = pk_bf16(acc[mb][nb][2] + bias, acc[mb][nb][3] + bias);
        *(uint2*)&Osel[((size_t)((b * NHH + h) * HDD + d)) * SS + s] = w2;
      }
    }
  }
}

// ---------------------------------------------------------------------------
// Final projection GEMM: 128(m) x 64(n) tiles -> grid (16,32)=512 blocks
// (2/CU vs 1/CU at 128x128). fp32 row-major output.
// ---------------------------------------------------------------------------
__global__ __launch_bounds__(256) void gemm_out(const u16* __restrict__ X,
                                                const u16* __restrict__ W,
                                                float* __restrict__ Ofp) {
  __shared__ __align__(16) u16 As[128 * 32];
  __shared__ __align__(16) u16 Bs[64 * 32];
  const int tid = threadIdx.x;
  const int lane = tid & 63;
  const int wvu = __builtin_amdgcn_readfirstlane(tid >> 6);
  const int l15 = lane & 15;
  const int quad = lane >> 4;
  const int wm = wvu >> 1, wn = wvu & 1;
  const int m0 = blockIdx.y * 128;
  const int n0 = blockIdx.x * 64;
  const int lr = lane >> 2;
  const int lc = lane & 3;

  floatx4 acc[4][2];
#pragma unroll
  for (int i = 0; i < 4; ++i)
#pragma unroll
    for (int j = 0; j < 2; ++j) acc[i][j] = (floatx4){0.f, 0.f, 0.f, 0.f};

  const int scol = (lc ^ ((lr >> 1) & 3)) * 8;
  const int fsw = ((l15 >> 1) & 3);

  for (int k0 = 0; k0 < HH; k0 += 32) {
#pragma unroll
    for (int u = 0; u < 2; ++u) {
      int r = u * 64 + wvu * 16 + lr;
      gload_lds16(&X[(size_t)(m0 + r) * HH + k0 + scol],
                  &As[(u * 64 + wvu * 16) * 32]);
    }
    gload_lds16(&W[(size_t)(n0 + wvu * 16 + lr) * HH + k0 + scol],
                &Bs[(wvu * 16) * 32]);
    __syncthreads();
    bf16x8 af[4], bfr[2];
#pragma unroll
    for (int mb = 0; mb < 4; ++mb)
      af[mb] = *(const bf16x8*)&As[(wm * 64 + mb * 16 + l15) * 32 +
                                   ((quad ^ fsw) * 8)];
#pragma unroll
    for (int nb = 0; nb < 2; ++nb)
      bfr[nb] = *(const bf16x8*)&Bs[(wn * 32 + nb * 16 + l15) * 32 +
                                    ((quad ^ fsw) * 8)];
#pragma unroll
    for (int mb = 0; mb < 4; ++mb)
#pragma unroll
      for (int nb = 0; nb < 2; ++nb)
        acc[mb][nb] = __builtin_amdgcn_mfma_f32_16x16x32_bf16(
            af[mb], bfr[nb], acc[mb][nb], 0, 0, 0);
    __syncthreads();
  }

#pragma unroll
  for (int mb = 0; mb < 4; ++mb)
#pragma unroll
    for (int r = 0; r < 4; ++r) {
      int m = m0 + wm * 64 + mb * 16 + quad * 4 + r;
#pragma unroll
      for (int nb = 0; nb < 2; ++nb)
        Ofp[(size_t)m * HH + n0 + wn * 32 + nb * 16 + l15] = acc[mb][nb][r];
    }
}

// ---------------------------------------------------------------------------
// Flash attention, key-partitioned quadrant scheme. Block = 64 qrows, tile =
// 64 keys; wave (kh=wv>>1, qh=wv&1) owns keys kh*32..+31 x qrows qh*32..+31.
// S^T = K·Q^T per quadrant (C: key=quad*4+r, qrow=l15). PV uses the K-dim
// permutation trick: with pi(quad*8+j) = (j>>2)*16 + quad*4 + (j&3), the
// MFMA B-operand IS the C-layout P already in registers (8 cvt_pk, no LDS
// round-trip), and the V A-operand is 2 ds_read_b64 per 16-d block.
// No Ps buffer -> LDS 32 KB; dbuf K/Vt via global_load_lds + XOR swizzle.
// Partner waves (kh=0/1) combine O via one LDS exchange at block end.
//
// R1 VALU diet: raw v_exp_f32 (__builtin_amdgcn_exp2f, no OCML denormal
// scaffold; inputs pre-scaled by 0.125*log2e so range is safe), t-loop
// unrolled x2 with STATIC buffer selection (LDS reads become base+imm off
// two fixed bases, no per-iter cndmask), running prefetch pointers (no
// per-iter offset multiply), s_setprio(1) around both MFMA clusters (T5:
// +4-7% on attn, m191).
// ---------------------------------------------------------------------------
__global__ __launch_bounds__(256, 4) void attn_mfma(const u16* __restrict__ Qg,
                                                    const u16* __restrict__ Kg,
                                                    const u16* __restrict__ Vtg,
                                                    u16* __restrict__ A) {
  __shared__ __align__(16) u16 smem[16384];  // 32 KB
  u16* const Ks0 = smem;
  u16* const Ks1 = smem + 4096;
  u16* const Vs0 = smem + 8192;
  u16* const Vs1 = smem + 12288;
  float* const lpart = (float*)smem;        // [4][32]
  float* const Opart = (float*)smem + 128;  // [2][32][68]

  const int tid = threadIdx.x;
  const int lane = tid & 63;
  const int wv = __builtin_amdgcn_readfirstlane(tid >> 6);
  const int l15 = lane & 15, quad = lane >> 4;
  const int sw7 = l15 & 7;
  const int bh = blockIdx.x, qt = blockIdx.y;
  const size_t hb = (size_t)bh * SS * HDD;  // Q,K [bh][s][d]; Vt [bh][d][s]
  const int kh = wv >> 1;  // key-half
  const int qh = wv & 1;   // qrow-half

  // staging geometry: wave covers segs {wv*2, wv*2+1} of 8 rows each
  const int r8 = lane >> 3, c7 = lane & 7;
  const int cs = (c7 ^ r8) * 8;  // XOR-swizzled chunk (u16 offset)
  const u16* kgb[2];
  const u16* vgb[2];
#pragma unroll
  for (int u = 0; u < 2; ++u) {
    int row = (wv * 2 + u) * 8 + r8;
    kgb[u] = Kg + hb + (size_t)row * HDD + cs;
    vgb[u] = Vtg + hb + (size_t)row * SS + cs;
  }

  // stage Q (64x64) into Ks1 + first K/V tile into buf0
#pragma unroll
  for (int u = 0; u < 2; ++u) {
    int row = (wv * 2 + u) * 8 + r8;
    gload_lds16(&Qg[hb + (size_t)(qt * 64 + row) * HDD + cs],
                Ks1 + (wv * 2 + u) * 512);
    gload_lds16(kgb[u], Ks0 + (wv * 2 + u) * 512);
    gload_lds16(vgb[u], Vs0 + (wv * 2 + u) * 512);
  }
  __syncthreads();

  // Q B-frags (loop-invariant): qrows qh*32 + nb*16 + l15
  bf16x8 qf[2][2];
#pragma unroll
  for (int nb = 0; nb < 2; ++nb)
#pragma unroll
    for (int h2 = 0; h2 < 2; ++h2)
      qf[nb][h2] = *(const bf16x8*)&Ks1[(qh * 32 + nb * 16 + l15) * 64 +
                                        (((h2 * 4 + quad) ^ sw7) * 8)];
  __syncthreads();  // qf reads complete before t=1 staging overwrites Ks1

  float l_acc[2] = {0.f, 0.f};
  floatx4 o[4][2];
#pragma unroll
  for (int dmb = 0; dmb < 4; ++dmb)
#pragma unroll
    for (int nb = 0; nb < 2; ++nb) o[dmb][nb] = (floatx4){0.f, 0.f, 0.f, 0.f};

  // running prefetch pointers: next tile to stage (tile 1 at loop entry)
  const u16* kp[2];
  const u16* vp[2];
#pragma unroll
  for (int u = 0; u < 2; ++u) {
    kp[u] = kgb[u] + 64 * HDD;
    vp[u] = vgb[u] + 64;
  }

  // one key-tile compute, statically-addressed buffers
  auto tile_compute = [&](const u16* ks, const u16* vs) {
    // S^T quadrant: keys kh*32+kmb*16+quad*4+r, qrows qh*32+nb*16+l15
    floatx4 st[2][2];
    __builtin_amdgcn_s_setprio(1);
#pragma unroll
    for (int kmb = 0; kmb < 2; ++kmb) {
      int krow = kh * 32 + kmb * 16 + l15;
      bf16x8 ak0 = *(const bf16x8*)&ks[krow * 64 + ((quad ^ sw7) * 8)];
      bf16x8 ak1 = *(const bf16x8*)&ks[krow * 64 + (((4 + quad) ^ sw7) * 8)];
#pragma unroll
      for (int nb = 0; nb < 2; ++nb) {
        floatx4 z = (floatx4){0.f, 0.f, 0.f, 0.f};
        z = __builtin_amdgcn_mfma_f32_16x16x32_bf16(ak0, qf[nb][0], z, 0, 0, 0);
        z = __builtin_amdgcn_mfma_f32_16x16x32_bf16(ak1, qf[nb][1], z, 0, 0, 0);
        st[kmb][nb] = z;
      }
    }
    __builtin_amdgcn_s_setprio(0);

    // exp2 + pack P into MFMA-B layout (permutation trick, in-register).
    // raw v_exp_f32: inputs bounded (pre-scaled), underflow->0 is fine.
    bf16x8 bp[2];
#pragma unroll
    for (int nb = 0; nb < 2; ++nb) {
      float p00 = __builtin_amdgcn_exp2f(st[0][nb][0]);
      float p01 = __builtin_amdgcn_exp2f(st[0][nb][1]);
      float p02 = __builtin_amdgcn_exp2f(st[0][nb][2]);
      float p03 = __builtin_amdgcn_exp2f(st[0][nb][3]);
      float p10 = __builtin_amdgcn_exp2f(st[1][nb][0]);
      float p11 = __builtin_amdgcn_exp2f(st[1][nb][1]);
      float p12 = __builtin_amdgcn_exp2f(st[1][nb][2]);
      float p13 = __builtin_amdgcn_exp2f(st[1][nb][3]);
      l_acc[nb] += ((p00 + p01) + (p02 + p03)) + ((p10 + p11) + (p12 + p13));
      union { bf16x8 v; unsigned u[4]; } pu;
      pu.u[0] = pk_bf16(p00, p01);
      pu.u[1] = pk_bf16(p02, p03);
      pu.u[2] = pk_bf16(p10, p11);
      pu.u[3] = pk_bf16(p12, p13);
      bp[nb] = pu.v;
    }

    // O^T += V^T(perm) . P(perm): A elem j = Vt[d][kh*32+(j>>2)*16+quad*4+(j&3)]
    const int cb0 = kh * 4 + (quad >> 1);
    const int cb1 = cb0 + 2;
    const int sub = (quad & 1) * 4;
    __builtin_amdgcn_s_setprio(1);
#pragma unroll
    for (int dmb = 0; dmb < 4; ++dmb) {
      int vr = (dmb * 16 + l15) * 64;
      union { bf16x8 v; uint2 d2[2]; } au;
      au.d2[0] = *(const uint2*)&vs[vr + ((cb0 ^ sw7) * 8) + sub];
      au.d2[1] = *(const uint2*)&vs[vr + ((cb1 ^ sw7) * 8) + sub];
#pragma unroll
      for (int nb = 0; nb < 2; ++nb)
        o[dmb][nb] = __builtin_amdgcn_mfma_f32_16x16x32_bf16(au.v, bp[nb],
                                                             o[dmb][nb], 0, 0, 0);
    }
    __builtin_amdgcn_s_setprio(0);
  };

  for (int tt = 0; tt < SS / 64; tt += 2) {
    // half 0: prefetch tile tt+1 -> buf1 (tt+1 <= 31 always), compute buf0
#pragma unroll
    for (int u = 0; u < 2; ++u) {
      gload_lds16(kp[u], Ks1 + (wv * 2 + u) * 512);
      gload_lds16(vp[u], Vs1 + (wv * 2 + u) * 512);
      kp[u] += 64 * HDD;
      vp[u] += 64;
    }
    tile_compute(Ks0, Vs0);
    __syncthreads();

    // half 1: prefetch tile tt+2 -> buf0 (guarded), compute buf1
    if (tt < SS / 64 - 2) {
#pragma unroll
      for (int u = 0; u < 2; ++u) {
        gload_lds16(kp[u], Ks0 + (wv * 2 + u) * 512);
        gload_lds16(vp[u], Vs0 + (wv * 2 + u) * 512);
      }
    }
#pragma unroll
    for (int u = 0; u < 2; ++u) {
      kp[u] += 64 * HDD;
      vp[u] += 64;
    }
    tile_compute(Ks1, Vs1);
    __syncthreads();
  }

  // ---- epilogue: combine key-halves ----
  // l: reduce over quads (16 keys of this wave), publish per-wave partial
#pragma unroll
  for (int nb = 0; nb < 2; ++nb) {
    l_acc[nb] += __shfl_xor(l_acc[nb], 16);
    l_acc[nb] += __shfl_xor(l_acc[nb], 32);
  }
  if (quad == 0) {
    lpart[wv * 32 + l15] = l_acc[0];
    lpart[wv * 32 + 16 + l15] = l_acc[1];
  }
  // O: waves kh==1 publish partial (qrow-major rows of 68 fp32)
  if (kh == 1) {
    float* dst = Opart + qh * (32 * 68);
#pragma unroll
    for (int nb = 0; nb < 2; ++nb)
#pragma unroll
      for (int dmb = 0; dmb < 4; ++dmb)
        *(floatx4*)&dst[(nb * 16 + l15) * 68 + dmb * 16 + quad * 4] =
            o[dmb][nb];
  }
  __syncthreads();
  if (kh == 0) {
    const int b = bh >> 4, h = bh & 15;
    const float* src = Opart + qh * (32 * 68);
    float inv[2];
#pragma unroll
    for (int nb = 0; nb < 2; ++nb)
      inv[nb] = 1.f / (lpart[wv * 32 + nb * 16 + l15] +
                       lpart[(wv + 2) * 32 + nb * 16 + l15]);
#pragma unroll
    for (int nb = 0; nb < 2; ++nb) {
      int s = qt * 64 + qh * 32 + nb * 16 + l15;
#pragma unroll
      for (int dmb = 0; dmb < 4; ++dmb) {
        floatx4 part =
            *(const floatx4*)&src[(nb * 16 + l15) * 68 + dmb * 16 + quad * 4];
        floatx4 tot = (o[dmb][nb] + part) * inv[nb];
        uint2 w2;
        w2.x = pk_bf16(tot[0], tot[1]);
        w2.y = pk_bf16(tot[2], tot[3]);
        *(uint2*)&A[((size_t)(b * SS + s) * HH) + h * HDD + dmb * 16 +
                    quad * 4] = w2;
      }
    }
  }
}

// ---------------------------------------------------------------------------
extern "C" void kernel_launch(void* const* d_in, const int* in_sizes, int n_in,
                              void* d_out, int out_size, void* d_ws,
                              size_t ws_size, hipStream_t stream) {
  const float* hs = (const float*)d_in[0];
  const int* pos = (const int*)d_in[1];
  const float* Wq = (const float*)d_in[2];
  const float* bq = (const float*)d_in[3];
  const float* Wk = (const float*)d_in[4];
  const float* bk = (const float*)d_in[5];
  const float* Wv = (const float*)d_in[6];
  const float* bv = (const float*)d_in[7];
  const float* Wo = (const float*)d_in[8];
  float* out = (float*)d_out;

  u16* hs_b = (u16*)d_ws;      // 4M
  u16* wq_b = hs_b + 4194304;  // 1M each
  u16* wk_b = wq_b + 1048576;
  u16* wv_b = wk_b + 1048576;
  u16* wo_b = wv_b + 1048576;
  u16* Qb = wo_b + 1048576;    // 4M each
  u16* Kb = Qb + 4194304;
  u16* Vtb = Kb + 4194304;     // transposed V [bh][d][s]
  u16* Ab = Vtb + 4194304;
  float2* tab = (float2*)(Ab + 4194304);  // [2048][32] cos/sin

  hipLaunchKernelGGL(convert_bf, dim3(8448), dim3(256), 0, stream, hs, Wq, Wk,
                     Wv, Wo, pos, hs_b, wq_b, wk_b, wv_b, wo_b, tab);
  hipLaunchKernelGGL(mfma_gemm_qkv, dim3(24, 32), dim3(256), 0, stream, hs_b,
                     wq_b, wk_b, wv_b, bq, bk, bv, tab, Qb, Kb, Vtb);
  hipLaunchKernelGGL(attn_mfma, dim3(32, 32), dim3(256), 0, stream, Qb, Kb,
                     Vtb, Ab);
  hipLaunchKernelGGL(gemm_out, dim3(16, 32), dim3(256), 0, stream, Ab, wo_b,
                     out);
}

// Round 3
// 191.415 us; speedup vs baseline: 1.1482x; 1.0505x over previous
//
#include <hip/hip_runtime.h>
#include <hip/hip_bf16.h>
#include <math.h>

#define SS 2048
#define HH 1024
#define NHH 16
#define HDD 64
#define BH 32
#define MM 4096

typedef unsigned short u16;
using bf16x8 = __attribute__((ext_vector_type(8))) short;
using floatx4 = __attribute__((ext_vector_type(4))) float;

__device__ __forceinline__ u16 f2bf(float f) {
  unsigned u = __float_as_uint(f);
  u += 0x7fffu + ((u >> 16) & 1u);
  return (u16)(u >> 16);
}
__device__ __forceinline__ unsigned pk_bf16(float a, float b) {
  union { __hip_bfloat162 h2; unsigned u; } c;
  c.h2 = __float22bfloat162_rn(float2{a, b});
  return c.u;
}
__device__ __forceinline__ void gload_lds16(const u16* g, u16* l) {
  __builtin_amdgcn_global_load_lds(
      (const __attribute__((address_space(1))) void*)g,
      (__attribute__((address_space(3))) void*)l, 16, 0, 0);
}

// ---------------------------------------------------------------------------
// fp32 -> bf16 conversion (hs + 4 weights) + RoPE cos/sin table.
// ---------------------------------------------------------------------------
__global__ __launch_bounds__(256) void convert_bf(
    const float* __restrict__ hs, const float* __restrict__ wq,
    const float* __restrict__ wk, const float* __restrict__ wv,
    const float* __restrict__ wo, const int* __restrict__ pos,
    u16* __restrict__ hs_b, u16* __restrict__ wq_b, u16* __restrict__ wk_b,
    u16* __restrict__ wv_b, u16* __restrict__ wo_b,
    float2* __restrict__ tab) {
  int g = blockIdx.x * 256 + threadIdx.x;
  if (g < 2097152) {
    const float* src;
    u16* dst;
    int off;
    if (g < 1048576) {
      src = hs; dst = hs_b; off = g;
    } else {
      int t = g - 1048576;
      int w = t >> 18;
      off = t & 262143;
      src = (w == 0) ? wq : (w == 1) ? wk : (w == 2) ? wv : wo;
      dst = (w == 0) ? wq_b : (w == 1) ? wk_b : (w == 2) ? wv_b : wo_b;
    }
    float4 v = ((const float4*)src)[off];
    ushort4 o = make_ushort4(f2bf(v.x), f2bf(v.y), f2bf(v.z), f2bf(v.w));
    ((ushort4*)dst)[off] = o;
  } else {
    int idx = g - 2097152;  // 0..65535
    int s = idx >> 5, j = idx & 31;
    float p = (float)pos[s];
    const float c0 = 13.287712379549449f / 32.0f;  // log2(10000)/32
    float f = p * exp2f(-(float)j * c0);
    float sn, cs;
    sincosf(f, &sn, &cs);
    tab[idx] = float2{cs, sn};
  }
}

// ---------------------------------------------------------------------------
// QKV GEMM, 8-phase 256x256 schedule (T2+T3+T4+T5), BK=64, 8 waves (2Mx4N),
// 128 KB STATIC LDS double-buffer, counted vmcnt(6) once per K-tile.
//
// Staging units are defined by READ-PHASE SET (fixes the R2 race):
//   UA_p0 = A rows {0-63,128-191}   (read only in phase 0)
//   UA_p2 = A rows {64-127,192-255} (read only in phase 2)
//   UB_p0 = B rows {wn*64+0..31}    (read only in phase 0)
//   UB_p1 = B rows {wn*64+32..63}   (read only in phase 1)
// Ring at tile t: p0 stages UB_p1(t+1) [other buf, dead since t-1];
//                 p1 stages UA_p0(t+2) [last read p0(t), barrier passed];
//                 p2 stages UB_p0(t+2) [last read p0(t)];
//                 p3 stages UA_p2(t+2) [last read p2(t)]; vmcnt(6)+barrier.
// vmcnt(6) keeps exactly the three t+2 units (6 loads) in flight and
// guarantees all of tile t+1 landed. Tail: t==14 -> vmcnt(0); t==15 no stage.
// Per-unit, per-wave dst is wave-uniform-base contiguous (16 rows = 2 gloads)
// so global_load_lds stays legal; chunk-XOR swizzle (c7^r8) on source + read.
// Q/K RoPE + V-transpose epilogues identical to R1; same K-accum order.
// Grid 192 = 3 wsel x 4 n x 16 m, bijective XCD swizzle (192 % 8 == 0).
// ---------------------------------------------------------------------------
__global__ __launch_bounds__(512, 2) void mfma_gemm_qkv(
    const u16* __restrict__ X, const u16* __restrict__ W0,
    const u16* __restrict__ W1, const u16* __restrict__ W2,
    const float* __restrict__ b0, const float* __restrict__ b1,
    const float* __restrict__ b2, const float2* __restrict__ tab,
    u16* __restrict__ O0, u16* __restrict__ O1, u16* __restrict__ O2) {
  __shared__ __align__(16) u16 lds[65536];  // 128 KB static
  const int tid = threadIdx.x;
  const int lane = tid & 63;
  const int wv = __builtin_amdgcn_readfirstlane(tid >> 6);
  const int l15 = lane & 15, quad = lane >> 4;
  const int sw7 = l15 & 7;
  const int wm = wv >> 2, wn = wv & 3;
  const int r8 = lane >> 3, c7 = lane & 7;

  // XCD-aware bijective swizzle: XCD x gets 24 contiguous (by,bx) tiles.
  int wg = blockIdx.x;
  int swz = (wg & 7) * 24 + (wg >> 3);
  int bx = swz % 12, by = swz / 12;
  const int m0 = by * 256;
  const int n0g = bx * 256;
  const int wsel = n0g >> 10;
  const int n0 = n0g & 1023;
  const u16* Wsel = (wsel == 1) ? W1 : (wsel == 2) ? W2 : W0;
  const float* bsel = (wsel == 1) ? b1 : (wsel == 2) ? b2 : b0;
  u16* Osel = (wsel == 1) ? O1 : (wsel == 2) ? O2 : O0;

  u16* const ldsA = lds;            // [buf][256][64] u16
  u16* const ldsB = lds + 32768;

  // per-unit global sources (2 gloads each), pre-swizzled chunk c7^r8
  const int csw = (c7 ^ r8) * 8;
  const int rA0 = (wv >> 2) * 128 + (wv & 3) * 16;  // UA_p0 per-wave base row
  const int rB0 = (wv >> 1) * 64 + (wv & 1) * 16;   // UB_p0 per-wave base row
  const u16* gA0a = X + (size_t)(m0 + rA0 + r8) * HH + csw;
  const u16* gA0b = gA0a + 8 * HH;
  const u16* gA2a = gA0a + 64 * HH;
  const u16* gA2b = gA0a + 72 * HH;
  const u16* gB0a = Wsel + (size_t)(n0 + rB0 + r8) * HH + csw;
  const u16* gB0b = gB0a + 8 * HH;
  const u16* gB1a = gB0a + 32 * HH;
  const u16* gB1b = gB0a + 40 * HH;
  // LDS dst offsets (u16), within buf (buf stride 16384)
  const int dA0 = rA0 * 64;
  const int dA2 = dA0 + 4096;   // +64 rows
  const int dB0 = rB0 * 64;
  const int dB1 = dB0 + 2048;   // +32 rows

#define STAGEU(pa, pb, base, doff, buf)                  \
  do {                                                   \
    u16* d_ = (base) + (buf) * 16384 + (doff);           \
    gload_lds16((pa), d_);                               \
    gload_lds16((pb), d_ + 512);                         \
  } while (0)

  floatx4 acc[8][4];
#pragma unroll
  for (int i = 0; i < 8; ++i)
#pragma unroll
    for (int j = 0; j < 4; ++j) acc[i][j] = (floatx4){0.f, 0.f, 0.f, 0.f};

  // prologue: tile0 all 4 units, tile1 {UA_p0, UB_p0, UA_p2} (7 units);
  // UB_p1(1) arrives at t0/p0. vmcnt(6) -> tile0 landed, tile1's 3 in flight.
  STAGEU(gA0a, gA0b, ldsA, dA0, 0);
  STAGEU(gA2a, gA2b, ldsA, dA2, 0);
  STAGEU(gB0a, gB0b, ldsB, dB0, 0);
  STAGEU(gB1a, gB1b, ldsB, dB1, 0);
  STAGEU(gA0a + 64, gA0b + 64, ldsA, dA0, 1);
  STAGEU(gB0a + 64, gB0b + 64, ldsB, dB0, 1);
  STAGEU(gA2a + 64, gA2b + 64, ldsA, dA2, 1);
  asm volatile("s_waitcnt vmcnt(6)" ::: "memory");
  __builtin_amdgcn_s_barrier();

  // running prefetch pointers (u16 offsets advance 64 per tile)
  const u16 *pUB1a = gB1a + 64, *pUB1b = gB1b + 64;      // next target: tile 1
  const u16 *pUA0a = gA0a + 128, *pUA0b = gA0b + 128;    // next target: tile 2
  const u16 *pUB0a = gB0a + 128, *pUB0b = gB0b + 128;
  const u16 *pUA2a = gA2a + 128, *pUA2b = gA2b + 128;

  bf16x8 af[4][2], bf0[2][2], bf1[2][2];

#define LOADA(Ab, hm)                                                     \
  _Pragma("unroll") for (int mb = 0; mb < 4; ++mb) {                      \
    const u16* rp_ = (Ab) + (wm * 128 + (hm) * 64 + mb * 16 + l15) * 64;  \
    af[mb][0] = *(const bf16x8*)&rp_[((quad ^ sw7) * 8)];                 \
    af[mb][1] = *(const bf16x8*)&rp_[(((4 + quad) ^ sw7) * 8)];           \
  }
#define LOADB(dst, Bb, hn)                                                \
  _Pragma("unroll") for (int nq = 0; nq < 2; ++nq) {                      \
    const u16* rp_ = (Bb) + (wn * 64 + (hn) * 32 + nq * 16 + l15) * 64;   \
    dst[nq][0] = *(const bf16x8*)&rp_[((quad ^ sw7) * 8)];                \
    dst[nq][1] = *(const bf16x8*)&rp_[(((4 + quad) ^ sw7) * 8)];          \
  }
#define MFMAQ(bfh, hm, hn)                                                \
  _Pragma("unroll") for (int mb = 0; mb < 4; ++mb)                        \
  _Pragma("unroll") for (int nq = 0; nq < 2; ++nq) {                      \
    acc[(hm) * 4 + mb][(hn) * 2 + nq] =                                   \
        __builtin_amdgcn_mfma_f32_16x16x32_bf16(                          \
            af[mb][0], bfh[nq][0], acc[(hm) * 4 + mb][(hn) * 2 + nq], 0,  \
            0, 0);                                                        \
    acc[(hm) * 4 + mb][(hn) * 2 + nq] =                                   \
        __builtin_amdgcn_mfma_f32_16x16x32_bf16(                          \
            af[mb][1], bfh[nq][1], acc[(hm) * 4 + mb][(hn) * 2 + nq], 0,  \
            0, 0);                                                        \
  }

#pragma unroll 2
  for (int t = 0; t < 16; ++t) {
    const u16* Ac = ldsA + (t & 1) * 16384;
    const u16* Bc = ldsB + (t & 1) * 16384;
    const int nb1 = (t + 1) & 1;  // buf for tile t+1
    const int nb2 = t & 1;        // buf for tile t+2
    // ---- phase 0: reads UA_p0 + UB_p0 (12 ds_read_b128), stage UB_p1(t+1)
    LOADA(Ac, 0);
    LOADB(bf0, Bc, 0);
    if (t < 15) {
      STAGEU(pUB1a, pUB1b, ldsB, dB1, nb1);
      pUB1a += 64; pUB1b += 64;
    }
    __builtin_amdgcn_s_barrier();
    asm volatile("s_waitcnt lgkmcnt(0)" ::: "memory");
    __builtin_amdgcn_s_setprio(1);
    MFMAQ(bf0, 0, 0);
    __builtin_amdgcn_s_setprio(0);
    __builtin_amdgcn_s_barrier();
    // ---- phase 1: reads UB_p1, stage UA_p0(t+2) (last read p0, closed)
    LOADB(bf1, Bc, 1);
    if (t < 14) {
      STAGEU(pUA0a, pUA0b, ldsA, dA0, nb2);
      pUA0a += 64; pUA0b += 64;
    }
    __builtin_amdgcn_s_barrier();
    asm volatile("s_waitcnt lgkmcnt(0)" ::: "memory");
    __builtin_amdgcn_s_setprio(1);
    MFMAQ(bf1, 0, 1);
    __builtin_amdgcn_s_setprio(0);
    __builtin_amdgcn_s_barrier();
    // ---- phase 2: reads UA_p2, stage UB_p0(t+2) (last read p0, closed)
    LOADA(Ac, 1);
    if (t < 14) {
      STAGEU(pUB0a, pUB0b, ldsB, dB0, nb2);
      pUB0a += 64; pUB0b += 64;
    }
    __builtin_amdgcn_s_barrier();
    asm volatile("s_waitcnt lgkmcnt(0)" ::: "memory");
    __builtin_amdgcn_s_setprio(1);
    MFMAQ(bf0, 1, 0);
    __builtin_amdgcn_s_setprio(0);
    __builtin_amdgcn_s_barrier();
    // ---- phase 3: regs only, stage UA_p2(t+2) (last read p2, closed)
    if (t < 14) {
      STAGEU(pUA2a, pUA2b, ldsA, dA2, nb2);
      pUA2a += 64; pUA2b += 64;
    }
    __builtin_amdgcn_s_setprio(1);
    MFMAQ(bf1, 1, 1);
    __builtin_amdgcn_s_setprio(0);
    if (t < 14) {
      asm volatile("s_waitcnt vmcnt(6)" ::: "memory");
      __builtin_amdgcn_s_barrier();
    } else if (t == 14) {
      asm volatile("s_waitcnt vmcnt(0)" ::: "memory");
      __builtin_amdgcn_s_barrier();
    }
  }
#undef STAGEU
#undef LOADA
#undef LOADB
#undef MFMAQ

  if (wsel < 2) {
    const float qs = (wsel == 0) ? 0.125f * 1.44269504088896f : 1.0f;
    const int colb = n0 + wn * 64;
    const int h = colb >> 6;
    const float bias0 = bsel[colb + l15];
    const float bias1 = bsel[colb + 16 + l15];
    const float bias2 = bsel[colb + 32 + l15];
    const float bias3 = bsel[colb + 48 + l15];
#pragma unroll
    for (int mb = 0; mb < 8; ++mb)
#pragma unroll
      for (int r = 0; r < 4; ++r) {
        int m = m0 + wm * 128 + mb * 16 + quad * 4 + r;
        int b = m >> 11, s = m & (SS - 1);
        float2 t0 = tab[s * 32 + l15];
        float2 t1 = tab[s * 32 + 16 + l15];
        size_t obase = ((size_t)(b * NHH + h) * SS + s) * HDD;
        float x1 = acc[mb][0][r] + bias0;
        float x2 = acc[mb][2][r] + bias2;
        Osel[obase + l15] = f2bf((x1 * t0.x - x2 * t0.y) * qs);
        Osel[obase + 32 + l15] = f2bf((x2 * t0.x + x1 * t0.y) * qs);
        float y1 = acc[mb][1][r] + bias1;
        float y2 = acc[mb][3][r] + bias3;
        Osel[obase + 16 + l15] = f2bf((y1 * t1.x - y2 * t1.y) * qs);
        Osel[obase + 48 + l15] = f2bf((y2 * t1.x + y1 * t1.y) * qs);
      }
  } else {
#pragma unroll
    for (int nb = 0; nb < 4; ++nb) {
      int col = n0 + wn * 64 + nb * 16 + l15;
      int h = col >> 6, d = col & 63;
      float bias = bsel[col];
#pragma unroll
      for (int mb = 0; mb < 8; ++mb) {
        int m = m0 + wm * 128 + mb * 16 + quad * 4;
        int b = m >> 11, s = m & (SS - 1);
        uint2 w2;
        w2.x = pk_bf16(acc[mb][nb][0] + bias, acc[mb][nb][1] + bias);
        w2.y = pk_bf16(acc[mb][nb][2] + bias, acc[mb][nb][3] + bias);
        *(uint2*)&Osel[((size_t)((b * NHH + h) * HDD + d)) * SS + s] = w2;
      }
    }
  }
}

// ---------------------------------------------------------------------------
// Final projection GEMM: 128(m) x 64(n) tiles -> grid (16,32)=512 blocks
// (2/CU vs 1/CU at 128x128). fp32 row-major output.
// ---------------------------------------------------------------------------
__global__ __launch_bounds__(256) void gemm_out(const u16* __restrict__ X,
                                                const u16* __restrict__ W,
                                                float* __restrict__ Ofp) {
  __shared__ __align__(16) u16 As[128 * 32];
  __shared__ __align__(16) u16 Bs[64 * 32];
  const int tid = threadIdx.x;
  const int lane = tid & 63;
  const int wvu = __builtin_amdgcn_readfirstlane(tid >> 6);
  const int l15 = lane & 15;
  const int quad = lane >> 4;
  const int wm = wvu >> 1, wn = wvu & 1;
  const int m0 = blockIdx.y * 128;
  const int n0 = blockIdx.x * 64;
  const int lr = lane >> 2;
  const int lc = lane & 3;

  floatx4 acc[4][2];
#pragma unroll
  for (int i = 0; i < 4; ++i)
#pragma unroll
    for (int j = 0; j < 2; ++j) acc[i][j] = (floatx4){0.f, 0.f, 0.f, 0.f};

  const int scol = (lc ^ ((lr >> 1) & 3)) * 8;
  const int fsw = ((l15 >> 1) & 3);

  for (int k0 = 0; k0 < HH; k0 += 32) {
#pragma unroll
    for (int u = 0; u < 2; ++u) {
      int r = u * 64 + wvu * 16 + lr;
      gload_lds16(&X[(size_t)(m0 + r) * HH + k0 + scol],
                  &As[(u * 64 + wvu * 16) * 32]);
    }
    gload_lds16(&W[(size_t)(n0 + wvu * 16 + lr) * HH + k0 + scol],
                &Bs[(wvu * 16) * 32]);
    __syncthreads();
    bf16x8 af[4], bfr[2];
#pragma unroll
    for (int mb = 0; mb < 4; ++mb)
      af[mb] = *(const bf16x8*)&As[(wm * 64 + mb * 16 + l15) * 32 +
                                   ((quad ^ fsw) * 8)];
#pragma unroll
    for (int nb = 0; nb < 2; ++nb)
      bfr[nb] = *(const bf16x8*)&Bs[(wn * 32 + nb * 16 + l15) * 32 +
                                    ((quad ^ fsw) * 8)];
#pragma unroll
    for (int mb = 0; mb < 4; ++mb)
#pragma unroll
      for (int nb = 0; nb < 2; ++nb)
        acc[mb][nb] = __builtin_amdgcn_mfma_f32_16x16x32_bf16(
            af[mb], bfr[nb], acc[mb][nb], 0, 0, 0);
    __syncthreads();
  }

#pragma unroll
  for (int mb = 0; mb < 4; ++mb)
#pragma unroll
    for (int r = 0; r < 4; ++r) {
      int m = m0 + wm * 64 + mb * 16 + quad * 4 + r;
#pragma unroll
      for (int nb = 0; nb < 2; ++nb)
        Ofp[(size_t)m * HH + n0 + wn * 32 + nb * 16 + l15] = acc[mb][nb][r];
    }
}

// ---------------------------------------------------------------------------
// Flash attention, key-partitioned quadrant scheme (R1: raw v_exp_f32,
// static dbuf unroll x2, running prefetch pointers, setprio on MFMA).
// ---------------------------------------------------------------------------
__global__ __launch_bounds__(256, 4) void attn_mfma(const u16* __restrict__ Qg,
                                                    const u16* __restrict__ Kg,
                                                    const u16* __restrict__ Vtg,
                                                    u16* __restrict__ A) {
  __shared__ __align__(16) u16 smem[16384];  // 32 KB
  u16* const Ks0 = smem;
  u16* const Ks1 = smem + 4096;
  u16* const Vs0 = smem + 8192;
  u16* const Vs1 = smem + 12288;
  float* const lpart = (float*)smem;        // [4][32]
  float* const Opart = (float*)smem + 128;  // [2][32][68]

  const int tid = threadIdx.x;
  const int lane = tid & 63;
  const int wv = __builtin_amdgcn_readfirstlane(tid >> 6);
  const int l15 = lane & 15, quad = lane >> 4;
  const int sw7 = l15 & 7;
  const int bh = blockIdx.x, qt = blockIdx.y;
  const size_t hb = (size_t)bh * SS * HDD;  // Q,K [bh][s][d]; Vt [bh][d][s]
  const int kh = wv >> 1;  // key-half
  const int qh = wv & 1;   // qrow-half

  // staging geometry: wave covers segs {wv*2, wv*2+1} of 8 rows each
  const int r8 = lane >> 3, c7 = lane & 7;
  const int cs = (c7 ^ r8) * 8;  // XOR-swizzled chunk (u16 offset)
  const u16* kgb[2];
  const u16* vgb[2];
#pragma unroll
  for (int u = 0; u < 2; ++u) {
    int row = (wv * 2 + u) * 8 + r8;
    kgb[u] = Kg + hb + (size_t)row * HDD + cs;
    vgb[u] = Vtg + hb + (size_t)row * SS + cs;
  }

  // stage Q (64x64) into Ks1 + first K/V tile into buf0
#pragma unroll
  for (int u = 0; u < 2; ++u) {
    int row = (wv * 2 + u) * 8 + r8;
    gload_lds16(&Qg[hb + (size_t)(qt * 64 + row) * HDD + cs],
                Ks1 + (wv * 2 + u) * 512);
    gload_lds16(kgb[u], Ks0 + (wv * 2 + u) * 512);
    gload_lds16(vgb[u], Vs0 + (wv * 2 + u) * 512);
  }
  __syncthreads();

  // Q B-frags (loop-invariant): qrows qh*32 + nb*16 + l15
  bf16x8 qf[2][2];
#pragma unroll
  for (int nb = 0; nb < 2; ++nb)
#pragma unroll
    for (int h2 = 0; h2 < 2; ++h2)
      qf[nb][h2] = *(const bf16x8*)&Ks1[(qh * 32 + nb * 16 + l15) * 64 +
                                        (((h2 * 4 + quad) ^ sw7) * 8)];
  __syncthreads();  // qf reads complete before t=1 staging overwrites Ks1

  float l_acc[2] = {0.f, 0.f};
  floatx4 o[4][2];
#pragma unroll
  for (int dmb = 0; dmb < 4; ++dmb)
#pragma unroll
    for (int nb = 0; nb < 2; ++nb) o[dmb][nb] = (floatx4){0.f, 0.f, 0.f, 0.f};

  // running prefetch pointers: next tile to stage (tile 1 at loop entry)
  const u16* kp[2];
  const u16* vp[2];
#pragma unroll
  for (int u = 0; u < 2; ++u) {
    kp[u] = kgb[u] + 64 * HDD;
    vp[u] = vgb[u] + 64;
  }

  // one key-tile compute, statically-addressed buffers
  auto tile_compute = [&](const u16* ks, const u16* vs) {
    // S^T quadrant: keys kh*32+kmb*16+quad*4+r, qrows qh*32+nb*16+l15
    floatx4 st[2][2];
    __builtin_amdgcn_s_setprio(1);
#pragma unroll
    for (int kmb = 0; kmb < 2; ++kmb) {
      int krow = kh * 32 + kmb * 16 + l15;
      bf16x8 ak0 = *(const bf16x8*)&ks[krow * 64 + ((quad ^ sw7) * 8)];
      bf16x8 ak1 = *(const bf16x8*)&ks[krow * 64 + (((4 + quad) ^ sw7) * 8)];
#pragma unroll
      for (int nb = 0; nb < 2; ++nb) {
        floatx4 z = (floatx4){0.f, 0.f, 0.f, 0.f};
        z = __builtin_amdgcn_mfma_f32_16x16x32_bf16(ak0, qf[nb][0], z, 0, 0, 0);
        z = __builtin_amdgcn_mfma_f32_16x16x32_bf16(ak1, qf[nb][1], z, 0, 0, 0);
        st[kmb][nb] = z;
      }
    }
    __builtin_amdgcn_s_setprio(0);

    // exp2 + pack P into MFMA-B layout (permutation trick, in-register).
    // raw v_exp_f32: inputs bounded (pre-scaled), underflow->0 is fine.
    bf16x8 bp[2];
#pragma unroll
    for (int nb = 0; nb < 2; ++nb) {
      float p00 = __builtin_amdgcn_exp2f(st[0][nb][0]);
      float p01 = __builtin_amdgcn_exp2f(st[0][nb][1]);
      float p02 = __builtin_amdgcn_exp2f(st[0][nb][2]);
      float p03 = __builtin_amdgcn_exp2f(st[0][nb][3]);
      float p10 = __builtin_amdgcn_exp2f(st[1][nb][0]);
      float p11 = __builtin_amdgcn_exp2f(st[1][nb][1]);
      float p12 = __builtin_amdgcn_exp2f(st[1][nb][2]);
      float p13 = __builtin_amdgcn_exp2f(st[1][nb][3]);
      l_acc[nb] += ((p00 + p01) + (p02 + p03)) + ((p10 + p11) + (p12 + p13));
      union { bf16x8 v; unsigned u[4]; } pu;
      pu.u[0] = pk_bf16(p00, p01);
      pu.u[1] = pk_bf16(p02, p03);
      pu.u[2] = pk_bf16(p10, p11);
      pu.u[3] = pk_bf16(p12, p13);
      bp[nb] = pu.v;
    }

    // O^T += V^T(perm) . P(perm): A elem j = Vt[d][kh*32+(j>>2)*16+quad*4+(j&3)]
    const int cb0 = kh * 4 + (quad >> 1);
    const int cb1 = cb0 + 2;
    const int sub = (quad & 1) * 4;
    __builtin_amdgcn_s_setprio(1);
#pragma unroll
    for (int dmb = 0; dmb < 4; ++dmb) {
      int vr = (dmb * 16 + l15) * 64;
      union { bf16x8 v; uint2 d2[2]; } au;
      au.d2[0] = *(const uint2*)&vs[vr + ((cb0 ^ sw7) * 8) + sub];
      au.d2[1] = *(const uint2*)&vs[vr + ((cb1 ^ sw7) * 8) + sub];
#pragma unroll
      for (int nb = 0; nb < 2; ++nb)
        o[dmb][nb] = __builtin_amdgcn_mfma_f32_16x16x32_bf16(au.v, bp[nb],
                                                             o[dmb][nb], 0, 0, 0);
    }
    __builtin_amdgcn_s_setprio(0);
  };

  for (int tt = 0; tt < SS / 64; tt += 2) {
    // half 0: prefetch tile tt+1 -> buf1 (tt+1 <= 31 always), compute buf0
#pragma unroll
    for (int u = 0; u < 2; ++u) {
      gload_lds16(kp[u], Ks1 + (wv * 2 + u) * 512);
      gload_lds16(vp[u], Vs1 + (wv * 2 + u) * 512);
      kp[u] += 64 * HDD;
      vp[u] += 64;
    }
    tile_compute(Ks0, Vs0);
    __syncthreads();

    // half 1: prefetch tile tt+2 -> buf0 (guarded), compute buf1
    if (tt < SS / 64 - 2) {
#pragma unroll
      for (int u = 0; u < 2; ++u) {
        gload_lds16(kp[u], Ks0 + (wv * 2 + u) * 512);
        gload_lds16(vp[u], Vs0 + (wv * 2 + u) * 512);
      }
    }
#pragma unroll
    for (int u = 0; u < 2; ++u) {
      kp[u] += 64 * HDD;
      vp[u] += 64;
    }
    tile_compute(Ks1, Vs1);
    __syncthreads();
  }

  // ---- epilogue: combine key-halves ----
  // l: reduce over quads (16 keys of this wave), publish per-wave partial
#pragma unroll
  for (int nb = 0; nb < 2; ++nb) {
    l_acc[nb] += __shfl_xor(l_acc[nb], 16);
    l_acc[nb] += __shfl_xor(l_acc[nb], 32);
  }
  if (quad == 0) {
    lpart[wv * 32 + l15] = l_acc[0];
    lpart[wv * 32 + 16 + l15] = l_acc[1];
  }
  // O: waves kh==1 publish partial (qrow-major rows of 68 fp32)
  if (kh == 1) {
    float* dst = Opart + qh * (32 * 68);
#pragma unroll
    for (int nb = 0; nb < 2; ++nb)
#pragma unroll
      for (int dmb = 0; dmb < 4; ++dmb)
        *(floatx4*)&dst[(nb * 16 + l15) * 68 + dmb * 16 + quad * 4] =
            o[dmb][nb];
  }
  __syncthreads();
  if (kh == 0) {
    const int b = bh >> 4, h = bh & 15;
    const float* src = Opart + qh * (32 * 68);
    float inv[2];
#pragma unroll
    for (int nb = 0; nb < 2; ++nb)
      inv[nb] = 1.f / (lpart[wv * 32 + nb * 16 + l15] +
                       lpart[(wv + 2) * 32 + nb * 16 + l15]);
#pragma unroll
    for (int nb = 0; nb < 2; ++nb) {
      int s = qt * 64 + qh * 32 + nb * 16 + l15;
#pragma unroll
      for (int dmb = 0; dmb < 4; ++dmb) {
        floatx4 part =
            *(const floatx4*)&src[(nb * 16 + l15) * 68 + dmb * 16 + quad * 4];
        floatx4 tot = (o[dmb][nb] + part) * inv[nb];
        uint2 w2;
        w2.x = pk_bf16(tot[0], tot[1]);
        w2.y = pk_bf16(tot[2], tot[3]);
        *(uint2*)&A[((size_t)(b * SS + s) * HH) + h * HDD + dmb * 16 +
                    quad * 4] = w2;
      }
    }
  }
}

// ---------------------------------------------------------------------------
extern "C" void kernel_launch(void* const* d_in, const int* in_sizes, int n_in,
                              void* d_out, int out_size, void* d_ws,
                              size_t ws_size, hipStream_t stream) {
  const float* hs = (const float*)d_in[0];
  const int* pos = (const int*)d_in[1];
  const float* Wq = (const float*)d_in[2];
  const float* bq = (const float*)d_in[3];
  const float* Wk = (const float*)d_in[4];
  const float* bk = (const float*)d_in[5];
  const float* Wv = (const float*)d_in[6];
  const float* bv = (const float*)d_in[7];
  const float* Wo = (const float*)d_in[8];
  float* out = (float*)d_out;

  u16* hs_b = (u16*)d_ws;      // 4M
  u16* wq_b = hs_b + 4194304;  // 1M each
  u16* wk_b = wq_b + 1048576;
  u16* wv_b = wk_b + 1048576;
  u16* wo_b = wv_b + 1048576;
  u16* Qb = wo_b + 1048576;    // 4M each
  u16* Kb = Qb + 4194304;
  u16* Vtb = Kb + 4194304;     // transposed V [bh][d][s]
  u16* Ab = Vtb + 4194304;
  float2* tab = (float2*)(Ab + 4194304);  // [2048][32] cos/sin

  hipLaunchKernelGGL(convert_bf, dim3(8448), dim3(256), 0, stream, hs, Wq, Wk,
                     Wv, Wo, pos, hs_b, wq_b, wk_b, wv_b, wo_b, tab);
  hipLaunchKernelGGL(mfma_gemm_qkv, dim3(192), dim3(512), 0, stream, hs_b,
                     wq_b, wk_b, wv_b, bq, bk, bv, tab, Qb, Kb, Vtb);
  hipLaunchKernelGGL(attn_mfma, dim3(32, 32), dim3(256), 0, stream, Qb, Kb,
                     Vtb, Ab);
  hipLaunchKernelGGL(gemm_out, dim3(16, 32), dim3(256), 0, stream, Ab, wo_b,
                     out);
}

// Round 4
// 186.307 us; speedup vs baseline: 1.1797x; 1.0274x over previous
//
#include <hip/hip_runtime.h>
#include <hip/hip_bf16.h>
#include <math.h>

#define SS 2048
#define HH 1024
#define NHH 16
#define HDD 64
#define BH 32
#define MM 4096

typedef unsigned short u16;
using bf16x8 = __attribute__((ext_vector_type(8))) short;
using floatx4 = __attribute__((ext_vector_type(4))) float;

__device__ __forceinline__ u16 f2bf(float f) {
  unsigned u = __float_as_uint(f);
  u += 0x7fffu + ((u >> 16) & 1u);
  return (u16)(u >> 16);
}
__device__ __forceinline__ unsigned pk_bf16(float a, float b) {
  union { __hip_bfloat162 h2; unsigned u; } c;
  c.h2 = __float22bfloat162_rn(float2{a, b});
  return c.u;
}
// single-instruction packed f32->bf16 (RNE). No builtin on gfx950 (m240);
// __float22bfloat162_rn may expand to the multi-op RNE bit sequence.
__device__ __forceinline__ unsigned pk_asm(float a, float b) {
  unsigned r;
  asm("v_cvt_pk_bf16_f32 %0, %1, %2" : "=v"(r) : "v"(a), "v"(b));
  return r;
}
__device__ __forceinline__ void gload_lds16(const u16* g, u16* l) {
  __builtin_amdgcn_global_load_lds(
      (const __attribute__((address_space(1))) void*)g,
      (__attribute__((address_space(3))) void*)l, 16, 0, 0);
}

// ---------------------------------------------------------------------------
// fp32 -> bf16 conversion (hs + 4 weights) + RoPE cos/sin table.
// ---------------------------------------------------------------------------
__global__ __launch_bounds__(256) void convert_bf(
    const float* __restrict__ hs, const float* __restrict__ wq,
    const float* __restrict__ wk, const float* __restrict__ wv,
    const float* __restrict__ wo, const int* __restrict__ pos,
    u16* __restrict__ hs_b, u16* __restrict__ wq_b, u16* __restrict__ wk_b,
    u16* __restrict__ wv_b, u16* __restrict__ wo_b,
    float2* __restrict__ tab) {
  int g = blockIdx.x * 256 + threadIdx.x;
  if (g < 2097152) {
    const float* src;
    u16* dst;
    int off;
    if (g < 1048576) {
      src = hs; dst = hs_b; off = g;
    } else {
      int t = g - 1048576;
      int w = t >> 18;
      off = t & 262143;
      src = (w == 0) ? wq : (w == 1) ? wk : (w == 2) ? wv : wo;
      dst = (w == 0) ? wq_b : (w == 1) ? wk_b : (w == 2) ? wv_b : wo_b;
    }
    float4 v = ((const float4*)src)[off];
    ushort4 o = make_ushort4(f2bf(v.x), f2bf(v.y), f2bf(v.z), f2bf(v.w));
    ((ushort4*)dst)[off] = o;
  } else {
    int idx = g - 2097152;  // 0..65535
    int s = idx >> 5, j = idx & 31;
    float p = (float)pos[s];
    const float c0 = 13.287712379549449f / 32.0f;  // log2(10000)/32
    float f = p * exp2f(-(float)j * c0);
    float sn, cs;
    sincosf(f, &sn, &cs);
    tab[idx] = float2{cs, sn};
  }
}

// ---------------------------------------------------------------------------
// QKV GEMM, 8-phase 256x256 schedule (T2+T3+T4+T5), BK=64, 8 waves (2Mx4N),
// 128 KB STATIC LDS double-buffer, counted vmcnt(6) once per K-tile.
// (unchanged from R3 — verified correct; ~44 us, limited by 192/256 CU fill)
// ---------------------------------------------------------------------------
__global__ __launch_bounds__(512, 2) void mfma_gemm_qkv(
    const u16* __restrict__ X, const u16* __restrict__ W0,
    const u16* __restrict__ W1, const u16* __restrict__ W2,
    const float* __restrict__ b0, const float* __restrict__ b1,
    const float* __restrict__ b2, const float2* __restrict__ tab,
    u16* __restrict__ O0, u16* __restrict__ O1, u16* __restrict__ O2) {
  __shared__ __align__(16) u16 lds[65536];  // 128 KB static
  const int tid = threadIdx.x;
  const int lane = tid & 63;
  const int wv = __builtin_amdgcn_readfirstlane(tid >> 6);
  const int l15 = lane & 15, quad = lane >> 4;
  const int sw7 = l15 & 7;
  const int wm = wv >> 2, wn = wv & 3;
  const int r8 = lane >> 3, c7 = lane & 7;

  // XCD-aware bijective swizzle: XCD x gets 24 contiguous (by,bx) tiles.
  int wg = blockIdx.x;
  int swz = (wg & 7) * 24 + (wg >> 3);
  int bx = swz % 12, by = swz / 12;
  const int m0 = by * 256;
  const int n0g = bx * 256;
  const int wsel = n0g >> 10;
  const int n0 = n0g & 1023;
  const u16* Wsel = (wsel == 1) ? W1 : (wsel == 2) ? W2 : W0;
  const float* bsel = (wsel == 1) ? b1 : (wsel == 2) ? b2 : b0;
  u16* Osel = (wsel == 1) ? O1 : (wsel == 2) ? O2 : O0;

  u16* const ldsA = lds;            // [buf][256][64] u16
  u16* const ldsB = lds + 32768;

  // per-unit global sources (2 gloads each), pre-swizzled chunk c7^r8
  const int csw = (c7 ^ r8) * 8;
  const int rA0 = (wv >> 2) * 128 + (wv & 3) * 16;  // UA_p0 per-wave base row
  const int rB0 = (wv >> 1) * 64 + (wv & 1) * 16;   // UB_p0 per-wave base row
  const u16* gA0a = X + (size_t)(m0 + rA0 + r8) * HH + csw;
  const u16* gA0b = gA0a + 8 * HH;
  const u16* gA2a = gA0a + 64 * HH;
  const u16* gA2b = gA0a + 72 * HH;
  const u16* gB0a = Wsel + (size_t)(n0 + rB0 + r8) * HH + csw;
  const u16* gB0b = gB0a + 8 * HH;
  const u16* gB1a = gB0a + 32 * HH;
  const u16* gB1b = gB0a + 40 * HH;
  // LDS dst offsets (u16), within buf (buf stride 16384)
  const int dA0 = rA0 * 64;
  const int dA2 = dA0 + 4096;   // +64 rows
  const int dB0 = rB0 * 64;
  const int dB1 = dB0 + 2048;   // +32 rows

#define STAGEU(pa, pb, base, doff, buf)                  \
  do {                                                   \
    u16* d_ = (base) + (buf) * 16384 + (doff);           \
    gload_lds16((pa), d_);                               \
    gload_lds16((pb), d_ + 512);                         \
  } while (0)

  floatx4 acc[8][4];
#pragma unroll
  for (int i = 0; i < 8; ++i)
#pragma unroll
    for (int j = 0; j < 4; ++j) acc[i][j] = (floatx4){0.f, 0.f, 0.f, 0.f};

  // prologue: tile0 all 4 units, tile1 {UA_p0, UB_p0, UA_p2} (7 units);
  // UB_p1(1) arrives at t0/p0. vmcnt(6) -> tile0 landed, tile1's 3 in flight.
  STAGEU(gA0a, gA0b, ldsA, dA0, 0);
  STAGEU(gA2a, gA2b, ldsA, dA2, 0);
  STAGEU(gB0a, gB0b, ldsB, dB0, 0);
  STAGEU(gB1a, gB1b, ldsB, dB1, 0);
  STAGEU(gA0a + 64, gA0b + 64, ldsA, dA0, 1);
  STAGEU(gB0a + 64, gB0b + 64, ldsB, dB0, 1);
  STAGEU(gA2a + 64, gA2b + 64, ldsA, dA2, 1);
  asm volatile("s_waitcnt vmcnt(6)" ::: "memory");
  __builtin_amdgcn_s_barrier();

  // running prefetch pointers (u16 offsets advance 64 per tile)
  const u16 *pUB1a = gB1a + 64, *pUB1b = gB1b + 64;      // next target: tile 1
  const u16 *pUA0a = gA0a + 128, *pUA0b = gA0b + 128;    // next target: tile 2
  const u16 *pUB0a = gB0a + 128, *pUB0b = gB0b + 128;
  const u16 *pUA2a = gA2a + 128, *pUA2b = gA2b + 128;

  bf16x8 af[4][2], bf0[2][2], bf1[2][2];

#define LOADA(Ab, hm)                                                     \
  _Pragma("unroll") for (int mb = 0; mb < 4; ++mb) {                      \
    const u16* rp_ = (Ab) + (wm * 128 + (hm) * 64 + mb * 16 + l15) * 64;  \
    af[mb][0] = *(const bf16x8*)&rp_[((quad ^ sw7) * 8)];                 \
    af[mb][1] = *(const bf16x8*)&rp_[(((4 + quad) ^ sw7) * 8)];           \
  }
#define LOADB(dst, Bb, hn)                                                \
  _Pragma("unroll") for (int nq = 0; nq < 2; ++nq) {                      \
    const u16* rp_ = (Bb) + (wn * 64 + (hn) * 32 + nq * 16 + l15) * 64;   \
    dst[nq][0] = *(const bf16x8*)&rp_[((quad ^ sw7) * 8)];                \
    dst[nq][1] = *(const bf16x8*)&rp_[(((4 + quad) ^ sw7) * 8)];          \
  }
#define MFMAQ(bfh, hm, hn)                                                \
  _Pragma("unroll") for (int mb = 0; mb < 4; ++mb)                        \
  _Pragma("unroll") for (int nq = 0; nq < 2; ++nq) {                      \
    acc[(hm) * 4 + mb][(hn) * 2 + nq] =                                   \
        __builtin_amdgcn_mfma_f32_16x16x32_bf16(                          \
            af[mb][0], bfh[nq][0], acc[(hm) * 4 + mb][(hn) * 2 + nq], 0,  \
            0, 0);                                                        \
    acc[(hm) * 4 + mb][(hn) * 2 + nq] =                                   \
        __builtin_amdgcn_mfma_f32_16x16x32_bf16(                          \
            af[mb][1], bfh[nq][1], acc[(hm) * 4 + mb][(hn) * 2 + nq], 0,  \
            0, 0);                                                        \
  }

#pragma unroll 2
  for (int t = 0; t < 16; ++t) {
    const u16* Ac = ldsA + (t & 1) * 16384;
    const u16* Bc = ldsB + (t & 1) * 16384;
    const int nb1 = (t + 1) & 1;  // buf for tile t+1
    const int nb2 = t & 1;        // buf for tile t+2
    // ---- phase 0: reads UA_p0 + UB_p0 (12 ds_read_b128), stage UB_p1(t+1)
    LOADA(Ac, 0);
    LOADB(bf0, Bc, 0);
    if (t < 15) {
      STAGEU(pUB1a, pUB1b, ldsB, dB1, nb1);
      pUB1a += 64; pUB1b += 64;
    }
    __builtin_amdgcn_s_barrier();
    asm volatile("s_waitcnt lgkmcnt(0)" ::: "memory");
    __builtin_amdgcn_s_setprio(1);
    MFMAQ(bf0, 0, 0);
    __builtin_amdgcn_s_setprio(0);
    __builtin_amdgcn_s_barrier();
    // ---- phase 1: reads UB_p1, stage UA_p0(t+2) (last read p0, closed)
    LOADB(bf1, Bc, 1);
    if (t < 14) {
      STAGEU(pUA0a, pUA0b, ldsA, dA0, nb2);
      pUA0a += 64; pUA0b += 64;
    }
    __builtin_amdgcn_s_barrier();
    asm volatile("s_waitcnt lgkmcnt(0)" ::: "memory");
    __builtin_amdgcn_s_setprio(1);
    MFMAQ(bf1, 0, 1);
    __builtin_amdgcn_s_setprio(0);
    __builtin_amdgcn_s_barrier();
    // ---- phase 2: reads UA_p2, stage UB_p0(t+2) (last read p0, closed)
    LOADA(Ac, 1);
    if (t < 14) {
      STAGEU(pUB0a, pUB0b, ldsB, dB0, nb2);
      pUB0a += 64; pUB0b += 64;
    }
    __builtin_amdgcn_s_barrier();
    asm volatile("s_waitcnt lgkmcnt(0)" ::: "memory");
    __builtin_amdgcn_s_setprio(1);
    MFMAQ(bf0, 1, 0);
    __builtin_amdgcn_s_setprio(0);
    __builtin_amdgcn_s_barrier();
    // ---- phase 3: regs only, stage UA_p2(t+2) (last read p2, closed)
    if (t < 14) {
      STAGEU(pUA2a, pUA2b, ldsA, dA2, nb2);
      pUA2a += 64; pUA2b += 64;
    }
    __builtin_amdgcn_s_setprio(1);
    MFMAQ(bf1, 1, 1);
    __builtin_amdgcn_s_setprio(0);
    if (t < 14) {
      asm volatile("s_waitcnt vmcnt(6)" ::: "memory");
      __builtin_amdgcn_s_barrier();
    } else if (t == 14) {
      asm volatile("s_waitcnt vmcnt(0)" ::: "memory");
      __builtin_amdgcn_s_barrier();
    }
  }
#undef STAGEU
#undef LOADA
#undef LOADB
#undef MFMAQ

  if (wsel < 2) {
    const float qs = (wsel == 0) ? 0.125f * 1.44269504088896f : 1.0f;
    const int colb = n0 + wn * 64;
    const int h = colb >> 6;
    const float bias0 = bsel[colb + l15];
    const float bias1 = bsel[colb + 16 + l15];
    const float bias2 = bsel[colb + 32 + l15];
    const float bias3 = bsel[colb + 48 + l15];
#pragma unroll
    for (int mb = 0; mb < 8; ++mb)
#pragma unroll
      for (int r = 0; r < 4; ++r) {
        int m = m0 + wm * 128 + mb * 16 + quad * 4 + r;
        int b = m >> 11, s = m & (SS - 1);
        float2 t0 = tab[s * 32 + l15];
        float2 t1 = tab[s * 32 + 16 + l15];
        size_t obase = ((size_t)(b * NHH + h) * SS + s) * HDD;
        float x1 = acc[mb][0][r] + bias0;
        float x2 = acc[mb][2][r] + bias2;
        Osel[obase + l15] = f2bf((x1 * t0.x - x2 * t0.y) * qs);
        Osel[obase + 32 + l15] = f2bf((x2 * t0.x + x1 * t0.y) * qs);
        float y1 = acc[mb][1][r] + bias1;
        float y2 = acc[mb][3][r] + bias3;
        Osel[obase + 16 + l15] = f2bf((y1 * t1.x - y2 * t1.y) * qs);
        Osel[obase + 48 + l15] = f2bf((y2 * t1.x + y1 * t1.y) * qs);
      }
  } else {
#pragma unroll
    for (int nb = 0; nb < 4; ++nb) {
      int col = n0 + wn * 64 + nb * 16 + l15;
      int h = col >> 6, d = col & 63;
      float bias = bsel[col];
#pragma unroll
      for (int mb = 0; mb < 8; ++mb) {
        int m = m0 + wm * 128 + mb * 16 + quad * 4;
        int b = m >> 11, s = m & (SS - 1);
        uint2 w2;
        w2.x = pk_bf16(acc[mb][nb][0] + bias, acc[mb][nb][1] + bias);
        w2.y = pk_bf16(acc[mb][nb][2] + bias, acc[mb][nb][3] + bias);
        *(uint2*)&Osel[((size_t)((b * NHH + h) * HDD + d)) * SS + s] = w2;
      }
    }
  }
}

// ---------------------------------------------------------------------------
// Final projection GEMM: 128(m) x 64(n) tiles -> grid (16,32)=512 blocks
// (2/CU vs 1/CU at 128x128). fp32 row-major output.
// ---------------------------------------------------------------------------
__global__ __launch_bounds__(256) void gemm_out(const u16* __restrict__ X,
                                                const u16* __restrict__ W,
                                                float* __restrict__ Ofp) {
  __shared__ __align__(16) u16 As[128 * 32];
  __shared__ __align__(16) u16 Bs[64 * 32];
  const int tid = threadIdx.x;
  const int lane = tid & 63;
  const int wvu = __builtin_amdgcn_readfirstlane(tid >> 6);
  const int l15 = lane & 15;
  const int quad = lane >> 4;
  const int wm = wvu >> 1, wn = wvu & 1;
  const int m0 = blockIdx.y * 128;
  const int n0 = blockIdx.x * 64;
  const int lr = lane >> 2;
  const int lc = lane & 3;

  floatx4 acc[4][2];
#pragma unroll
  for (int i = 0; i < 4; ++i)
#pragma unroll
    for (int j = 0; j < 2; ++j) acc[i][j] = (floatx4){0.f, 0.f, 0.f, 0.f};

  const int scol = (lc ^ ((lr >> 1) & 3)) * 8;
  const int fsw = ((l15 >> 1) & 3);

  for (int k0 = 0; k0 < HH; k0 += 32) {
#pragma unroll
    for (int u = 0; u < 2; ++u) {
      int r = u * 64 + wvu * 16 + lr;
      gload_lds16(&X[(size_t)(m0 + r) * HH + k0 + scol],
                  &As[(u * 64 + wvu * 16) * 32]);
    }
    gload_lds16(&W[(size_t)(n0 + wvu * 16 + lr) * HH + k0 + scol],
                &Bs[(wvu * 16) * 32]);
    __syncthreads();
    bf16x8 af[4], bfr[2];
#pragma unroll
    for (int mb = 0; mb < 4; ++mb)
      af[mb] = *(const bf16x8*)&As[(wm * 64 + mb * 16 + l15) * 32 +
                                   ((quad ^ fsw) * 8)];
#pragma unroll
    for (int nb = 0; nb < 2; ++nb)
      bfr[nb] = *(const bf16x8*)&Bs[(wn * 32 + nb * 16 + l15) * 32 +
                                    ((quad ^ fsw) * 8)];
#pragma unroll
    for (int mb = 0; mb < 4; ++mb)
#pragma unroll
      for (int nb = 0; nb < 2; ++nb)
        acc[mb][nb] = __builtin_amdgcn_mfma_f32_16x16x32_bf16(
            af[mb], bfr[nb], acc[mb][nb], 0, 0, 0);
    __syncthreads();
  }

#pragma unroll
  for (int mb = 0; mb < 4; ++mb)
#pragma unroll
    for (int r = 0; r < 4; ++r) {
      int m = m0 + wm * 64 + mb * 16 + quad * 4 + r;
#pragma unroll
      for (int nb = 0; nb < 2; ++nb)
        Ofp[(size_t)m * HH + n0 + wn * 32 + nb * 16 + l15] = acc[mb][nb][r];
    }
}

// ---------------------------------------------------------------------------
// Flash attention, key-partitioned quadrant scheme.
// R4 VALU diet: (1) all f32->bf16 packing via single-instruction
// v_cvt_pk_bf16_f32 inline asm (no builtin exists; __float22bfloat162_rn may
// expand to the multi-op RNE sequence); (2) staging addresses rewritten as
// uniform base + loop-invariant per-lane offset so the per-tile advance is
// scalar (saddr+voffset form) instead of 4x 64-bit per-lane pointer adds.
// Schedule/barriers/numerics unchanged from R1/R3.
// ---------------------------------------------------------------------------
__global__ __launch_bounds__(256, 4) void attn_mfma(const u16* __restrict__ Qg,
                                                    const u16* __restrict__ Kg,
                                                    const u16* __restrict__ Vtg,
                                                    u16* __restrict__ A) {
  __shared__ __align__(16) u16 smem[16384];  // 32 KB
  u16* const Ks0 = smem;
  u16* const Ks1 = smem + 4096;
  u16* const Vs0 = smem + 8192;
  u16* const Vs1 = smem + 12288;
  float* const lpart = (float*)smem;        // [4][32]
  float* const Opart = (float*)smem + 128;  // [2][32][68]

  const int tid = threadIdx.x;
  const int lane = tid & 63;
  const int wv = __builtin_amdgcn_readfirstlane(tid >> 6);
  const int l15 = lane & 15, quad = lane >> 4;
  const int sw7 = l15 & 7;
  const int bh = blockIdx.x, qt = blockIdx.y;
  const size_t hb = (size_t)bh * SS * HDD;  // Q,K [bh][s][d]; Vt [bh][d][s]
  const int kh = wv >> 1;  // key-half
  const int qh = wv & 1;   // qrow-half

  // staging geometry: wave covers segs {wv*2, wv*2+1} of 8 rows each.
  // uniform bases + loop-invariant per-lane offsets (scalar tile advance).
  const int r8 = lane >> 3, c7 = lane & 7;
  const int cs = (c7 ^ r8) * 8;  // XOR-swizzled chunk (u16 offset)
  const u16* const Kt = Kg + hb;
  const u16* const Vt = Vtg + hb;
  const int row0 = (wv * 2 + 0) * 8 + r8;
  const int row1 = (wv * 2 + 1) * 8 + r8;
  const int koff0 = row0 * HDD + cs;
  const int koff1 = row1 * HDD + cs;
  const int voff0 = row0 * SS + cs;
  const int voff1 = row1 * SS + cs;
  u16* const kd0 = smem + (wv * 2 + 0) * 512;  // LDS dst (buf-relative)
  u16* const kd1 = smem + (wv * 2 + 1) * 512;

  // stage Q (64x64) into Ks1 + first K/V tile into buf0
  gload_lds16(Qg + hb + qt * 4096 + koff0, kd0 + 4096);
  gload_lds16(Qg + hb + qt * 4096 + koff1, kd1 + 4096);
  gload_lds16(Kt + koff0, kd0);
  gload_lds16(Kt + koff1, kd1);
  gload_lds16(Vt + voff0, kd0 + 8192);
  gload_lds16(Vt + voff1, kd1 + 8192);
  __syncthreads();

  // Q B-frags (loop-invariant): qrows qh*32 + nb*16 + l15
  bf16x8 qf[2][2];
#pragma unroll
  for (int nb = 0; nb < 2; ++nb)
#pragma unroll
    for (int h2 = 0; h2 < 2; ++h2)
      qf[nb][h2] = *(const bf16x8*)&Ks1[(qh * 32 + nb * 16 + l15) * 64 +
                                        (((h2 * 4 + quad) ^ sw7) * 8)];
  __syncthreads();  // qf reads complete before t=1 staging overwrites Ks1

  float l_acc[2] = {0.f, 0.f};
  floatx4 o[4][2];
#pragma unroll
  for (int dmb = 0; dmb < 4; ++dmb)
#pragma unroll
    for (int nb = 0; nb < 2; ++nb) o[dmb][nb] = (floatx4){0.f, 0.f, 0.f, 0.f};

  // one key-tile compute, statically-addressed buffers
  auto tile_compute = [&](const u16* ks, const u16* vs) {
    // S^T quadrant: keys kh*32+kmb*16+quad*4+r, qrows qh*32+nb*16+l15
    floatx4 st[2][2];
    __builtin_amdgcn_s_setprio(1);
#pragma unroll
    for (int kmb = 0; kmb < 2; ++kmb) {
      int krow = kh * 32 + kmb * 16 + l15;
      bf16x8 ak0 = *(const bf16x8*)&ks[krow * 64 + ((quad ^ sw7) * 8)];
      bf16x8 ak1 = *(const bf16x8*)&ks[krow * 64 + (((4 + quad) ^ sw7) * 8)];
#pragma unroll
      for (int nb = 0; nb < 2; ++nb) {
        floatx4 z = (floatx4){0.f, 0.f, 0.f, 0.f};
        z = __builtin_amdgcn_mfma_f32_16x16x32_bf16(ak0, qf[nb][0], z, 0, 0, 0);
        z = __builtin_amdgcn_mfma_f32_16x16x32_bf16(ak1, qf[nb][1], z, 0, 0, 0);
        st[kmb][nb] = z;
      }
    }
    __builtin_amdgcn_s_setprio(0);

    // exp2 + pack P into MFMA-B layout (permutation trick, in-register).
    // raw v_exp_f32 + raw v_cvt_pk_bf16_f32.
    bf16x8 bp[2];
#pragma unroll
    for (int nb = 0; nb < 2; ++nb) {
      float p00 = __builtin_amdgcn_exp2f(st[0][nb][0]);
      float p01 = __builtin_amdgcn_exp2f(st[0][nb][1]);
      float p02 = __builtin_amdgcn_exp2f(st[0][nb][2]);
      float p03 = __builtin_amdgcn_exp2f(st[0][nb][3]);
      float p10 = __builtin_amdgcn_exp2f(st[1][nb][0]);
      float p11 = __builtin_amdgcn_exp2f(st[1][nb][1]);
      float p12 = __builtin_amdgcn_exp2f(st[1][nb][2]);
      float p13 = __builtin_amdgcn_exp2f(st[1][nb][3]);
      l_acc[nb] += ((p00 + p01) + (p02 + p03)) + ((p10 + p11) + (p12 + p13));
      union { bf16x8 v; unsigned u[4]; } pu;
      pu.u[0] = pk_asm(p00, p01);
      pu.u[1] = pk_asm(p02, p03);
      pu.u[2] = pk_asm(p10, p11);
      pu.u[3] = pk_asm(p12, p13);
      bp[nb] = pu.v;
    }

    // O^T += V^T(perm) . P(perm): A elem j = Vt[d][kh*32+(j>>2)*16+quad*4+(j&3)]
    const int cb0 = kh * 4 + (quad >> 1);
    const int cb1 = cb0 + 2;
    const int sub = (quad & 1) * 4;
    __builtin_amdgcn_s_setprio(1);
#pragma unroll
    for (int dmb = 0; dmb < 4; ++dmb) {
      int vr = (dmb * 16 + l15) * 64;
      union { bf16x8 v; uint2 d2[2]; } au;
      au.d2[0] = *(const uint2*)&vs[vr + ((cb0 ^ sw7) * 8) + sub];
      au.d2[1] = *(const uint2*)&vs[vr + ((cb1 ^ sw7) * 8) + sub];
#pragma unroll
      for (int nb = 0; nb < 2; ++nb)
        o[dmb][nb] = __builtin_amdgcn_mfma_f32_16x16x32_bf16(au.v, bp[nb],
                                                             o[dmb][nb], 0, 0, 0);
    }
    __builtin_amdgcn_s_setprio(0);
  };

  for (int tt = 0; tt < SS / 64; tt += 2) {
    // half 0: prefetch tile tt+1 -> buf1 (tt+1 <= 31 always), compute buf0
    {
      const int k1 = (tt + 1) * 64 * HDD;  // uniform
      const int v1 = (tt + 1) * 64;        // uniform
      gload_lds16(Kt + k1 + koff0, kd0 + 4096);
      gload_lds16(Kt + k1 + koff1, kd1 + 4096);
      gload_lds16(Vt + v1 + voff0, kd0 + 12288);
      gload_lds16(Vt + v1 + voff1, kd1 + 12288);
    }
    tile_compute(Ks0, Vs0);
    __syncthreads();

    // half 1: prefetch tile tt+2 -> buf0 (guarded), compute buf1
    if (tt < SS / 64 - 2) {
      const int k2 = (tt + 2) * 64 * HDD;
      const int v2 = (tt + 2) * 64;
      gload_lds16(Kt + k2 + koff0, kd0);
      gload_lds16(Kt + k2 + koff1, kd1);
      gload_lds16(Vt + v2 + voff0, kd0 + 8192);
      gload_lds16(Vt + v2 + voff1, kd1 + 8192);
    }
    tile_compute(Ks1, Vs1);
    __syncthreads();
  }

  // ---- epilogue: combine key-halves ----
  // l: reduce over quads (16 keys of this wave), publish per-wave partial
#pragma unroll
  for (int nb = 0; nb < 2; ++nb) {
    l_acc[nb] += __shfl_xor(l_acc[nb], 16);
    l_acc[nb] += __shfl_xor(l_acc[nb], 32);
  }
  if (quad == 0) {
    lpart[wv * 32 + l15] = l_acc[0];
    lpart[wv * 32 + 16 + l15] = l_acc[1];
  }
  // O: waves kh==1 publish partial (qrow-major rows of 68 fp32)
  if (kh == 1) {
    float* dst = Opart + qh * (32 * 68);
#pragma unroll
    for (int nb = 0; nb < 2; ++nb)
#pragma unroll
      for (int dmb = 0; dmb < 4; ++dmb)
        *(floatx4*)&dst[(nb * 16 + l15) * 68 + dmb * 16 + quad * 4] =
            o[dmb][nb];
  }
  __syncthreads();
  if (kh == 0) {
    const int b = bh >> 4, h = bh & 15;
    const float* src = Opart + qh * (32 * 68);
    float inv[2];
#pragma unroll
    for (int nb = 0; nb < 2; ++nb)
      inv[nb] = 1.f / (lpart[wv * 32 + nb * 16 + l15] +
                       lpart[(wv + 2) * 32 + nb * 16 + l15]);
#pragma unroll
    for (int nb = 0; nb < 2; ++nb) {
      int s = qt * 64 + qh * 32 + nb * 16 + l15;
#pragma unroll
      for (int dmb = 0; dmb < 4; ++dmb) {
        floatx4 part =
            *(const floatx4*)&src[(nb * 16 + l15) * 68 + dmb * 16 + quad * 4];
        floatx4 tot = (o[dmb][nb] + part) * inv[nb];
        uint2 w2;
        w2.x = pk_asm(tot[0], tot[1]);
        w2.y = pk_asm(tot[2], tot[3]);
        *(uint2*)&A[((size_t)(b * SS + s) * HH) + h * HDD + dmb * 16 +
                    quad * 4] = w2;
      }
    }
  }
}

// ---------------------------------------------------------------------------
extern "C" void kernel_launch(void* const* d_in, const int* in_sizes, int n_in,
                              void* d_out, int out_size, void* d_ws,
                              size_t ws_size, hipStream_t stream) {
  const float* hs = (const float*)d_in[0];
  const int* pos = (const int*)d_in[1];
  const float* Wq = (const float*)d_in[2];
  const float* bq = (const float*)d_in[3];
  const float* Wk = (const float*)d_in[4];
  const float* bk = (const float*)d_in[5];
  const float* Wv = (const float*)d_in[6];
  const float* bv = (const float*)d_in[7];
  const float* Wo = (const float*)d_in[8];
  float* out = (float*)d_out;

  u16* hs_b = (u16*)d_ws;      // 4M
  u16* wq_b = hs_b + 4194304;  // 1M each
  u16* wk_b = wq_b + 1048576;
  u16* wv_b = wk_b + 1048576;
  u16* wo_b = wv_b + 1048576;
  u16* Qb = wo_b + 1048576;    // 4M each
  u16* Kb = Qb + 4194304;
  u16* Vtb = Kb + 4194304;     // transposed V [bh][d][s]
  u16* Ab = Vtb + 4194304;
  float2* tab = (float2*)(Ab + 4194304);  // [2048][32] cos/sin

  hipLaunchKernelGGL(convert_bf, dim3(8448), dim3(256), 0, stream, hs, Wq, Wk,
                     Wv, Wo, pos, hs_b, wq_b, wk_b, wv_b, wo_b, tab);
  hipLaunchKernelGGL(mfma_gemm_qkv, dim3(192), dim3(512), 0, stream, hs_b,
                     wq_b, wk_b, wv_b, bq, bk, bv, tab, Qb, Kb, Vtb);
  hipLaunchKernelGGL(attn_mfma, dim3(32, 32), dim3(256), 0, stream, Qb, Kb,
                     Vtb, Ab);
  hipLaunchKernelGGL(gemm_out, dim3(16, 32), dim3(256), 0, stream, Ab, wo_b,
                     out);
}

// Round 5
// 178.932 us; speedup vs baseline: 1.2283x; 1.0412x over previous
//
#include <hip/hip_runtime.h>
#include <hip/hip_bf16.h>
#include <math.h>

#define SS 2048
#define HH 1024
#define NHH 16
#define HDD 64
#define BH 32
#define MM 4096

typedef unsigned short u16;
using bf16x8 = __attribute__((ext_vector_type(8))) short;
using floatx4 = __attribute__((ext_vector_type(4))) float;

__device__ __forceinline__ u16 f2bf(float f) {
  unsigned u = __float_as_uint(f);
  u += 0x7fffu + ((u >> 16) & 1u);
  return (u16)(u >> 16);
}
__device__ __forceinline__ unsigned pk_bf16(float a, float b) {
  union { __hip_bfloat162 h2; unsigned u; } c;
  c.h2 = __float22bfloat162_rn(float2{a, b});
  return c.u;
}
// single-instruction packed f32->bf16 (RNE). No builtin on gfx950 (m240).
__device__ __forceinline__ unsigned pk_asm(float a, float b) {
  unsigned r;
  asm("v_cvt_pk_bf16_f32 %0, %1, %2" : "=v"(r) : "v"(a), "v"(b));
  return r;
}
__device__ __forceinline__ void gload_lds16(const u16* g, u16* l) {
  __builtin_amdgcn_global_load_lds(
      (const __attribute__((address_space(1))) void*)g,
      (__attribute__((address_space(3))) void*)l, 16, 0, 0);
}

// ---------------------------------------------------------------------------
// fp32 -> bf16 conversion (hs + 4 weights) + RoPE cos/sin table.
// ---------------------------------------------------------------------------
__global__ __launch_bounds__(256) void convert_bf(
    const float* __restrict__ hs, const float* __restrict__ wq,
    const float* __restrict__ wk, const float* __restrict__ wv,
    const float* __restrict__ wo, const int* __restrict__ pos,
    u16* __restrict__ hs_b, u16* __restrict__ wq_b, u16* __restrict__ wk_b,
    u16* __restrict__ wv_b, u16* __restrict__ wo_b,
    float2* __restrict__ tab) {
  int g = blockIdx.x * 256 + threadIdx.x;
  if (g < 2097152) {
    const float* src;
    u16* dst;
    int off;
    if (g < 1048576) {
      src = hs; dst = hs_b; off = g;
    } else {
      int t = g - 1048576;
      int w = t >> 18;
      off = t & 262143;
      src = (w == 0) ? wq : (w == 1) ? wk : (w == 2) ? wv : wo;
      dst = (w == 0) ? wq_b : (w == 1) ? wk_b : (w == 2) ? wv_b : wo_b;
    }
    float4 v = ((const float4*)src)[off];
    ushort4 o = make_ushort4(f2bf(v.x), f2bf(v.y), f2bf(v.z), f2bf(v.w));
    ((ushort4*)dst)[off] = o;
  } else {
    int idx = g - 2097152;  // 0..65535
    int s = idx >> 5, j = idx & 31;
    float p = (float)pos[s];
    const float c0 = 13.287712379549449f / 32.0f;  // log2(10000)/32
    float f = p * exp2f(-(float)j * c0);
    float sn, cs;
    sincosf(f, &sn, &cs);
    tab[idx] = float2{cs, sn};
  }
}

// ---------------------------------------------------------------------------
// QKV GEMM, 8-phase 256x256 schedule (T2+T3+T4+T5), BK=64, 8 waves (2Mx4N),
// 128 KB STATIC LDS double-buffer, counted vmcnt(6) once per K-tile.
// (unchanged from R3 — verified correct; ~44 us, limited by 192/256 CU fill)
// ---------------------------------------------------------------------------
__global__ __launch_bounds__(512, 2) void mfma_gemm_qkv(
    const u16* __restrict__ X, const u16* __restrict__ W0,
    const u16* __restrict__ W1, const u16* __restrict__ W2,
    const float* __restrict__ b0, const float* __restrict__ b1,
    const float* __restrict__ b2, const float2* __restrict__ tab,
    u16* __restrict__ O0, u16* __restrict__ O1, u16* __restrict__ O2) {
  __shared__ __align__(16) u16 lds[65536];  // 128 KB static
  const int tid = threadIdx.x;
  const int lane = tid & 63;
  const int wv = __builtin_amdgcn_readfirstlane(tid >> 6);
  const int l15 = lane & 15, quad = lane >> 4;
  const int sw7 = l15 & 7;
  const int wm = wv >> 2, wn = wv & 3;
  const int r8 = lane >> 3, c7 = lane & 7;

  // XCD-aware bijective swizzle: XCD x gets 24 contiguous (by,bx) tiles.
  int wg = blockIdx.x;
  int swz = (wg & 7) * 24 + (wg >> 3);
  int bx = swz % 12, by = swz / 12;
  const int m0 = by * 256;
  const int n0g = bx * 256;
  const int wsel = n0g >> 10;
  const int n0 = n0g & 1023;
  const u16* Wsel = (wsel == 1) ? W1 : (wsel == 2) ? W2 : W0;
  const float* bsel = (wsel == 1) ? b1 : (wsel == 2) ? b2 : b0;
  u16* Osel = (wsel == 1) ? O1 : (wsel == 2) ? O2 : O0;

  u16* const ldsA = lds;            // [buf][256][64] u16
  u16* const ldsB = lds + 32768;

  // per-unit global sources (2 gloads each), pre-swizzled chunk c7^r8
  const int csw = (c7 ^ r8) * 8;
  const int rA0 = (wv >> 2) * 128 + (wv & 3) * 16;  // UA_p0 per-wave base row
  const int rB0 = (wv >> 1) * 64 + (wv & 1) * 16;   // UB_p0 per-wave base row
  const u16* gA0a = X + (size_t)(m0 + rA0 + r8) * HH + csw;
  const u16* gA0b = gA0a + 8 * HH;
  const u16* gA2a = gA0a + 64 * HH;
  const u16* gA2b = gA0a + 72 * HH;
  const u16* gB0a = Wsel + (size_t)(n0 + rB0 + r8) * HH + csw;
  const u16* gB0b = gB0a + 8 * HH;
  const u16* gB1a = gB0a + 32 * HH;
  const u16* gB1b = gB0a + 40 * HH;
  // LDS dst offsets (u16), within buf (buf stride 16384)
  const int dA0 = rA0 * 64;
  const int dA2 = dA0 + 4096;   // +64 rows
  const int dB0 = rB0 * 64;
  const int dB1 = dB0 + 2048;   // +32 rows

#define STAGEU(pa, pb, base, doff, buf)                  \
  do {                                                   \
    u16* d_ = (base) + (buf) * 16384 + (doff);           \
    gload_lds16((pa), d_);                               \
    gload_lds16((pb), d_ + 512);                         \
  } while (0)

  floatx4 acc[8][4];
#pragma unroll
  for (int i = 0; i < 8; ++i)
#pragma unroll
    for (int j = 0; j < 4; ++j) acc[i][j] = (floatx4){0.f, 0.f, 0.f, 0.f};

  // prologue: tile0 all 4 units, tile1 {UA_p0, UB_p0, UA_p2} (7 units);
  // UB_p1(1) arrives at t0/p0. vmcnt(6) -> tile0 landed, tile1's 3 in flight.
  STAGEU(gA0a, gA0b, ldsA, dA0, 0);
  STAGEU(gA2a, gA2b, ldsA, dA2, 0);
  STAGEU(gB0a, gB0b, ldsB, dB0, 0);
  STAGEU(gB1a, gB1b, ldsB, dB1, 0);
  STAGEU(gA0a + 64, gA0b + 64, ldsA, dA0, 1);
  STAGEU(gB0a + 64, gB0b + 64, ldsB, dB0, 1);
  STAGEU(gA2a + 64, gA2b + 64, ldsA, dA2, 1);
  asm volatile("s_waitcnt vmcnt(6)" ::: "memory");
  __builtin_amdgcn_s_barrier();

  // running prefetch pointers (u16 offsets advance 64 per tile)
  const u16 *pUB1a = gB1a + 64, *pUB1b = gB1b + 64;      // next target: tile 1
  const u16 *pUA0a = gA0a + 128, *pUA0b = gA0b + 128;    // next target: tile 2
  const u16 *pUB0a = gB0a + 128, *pUB0b = gB0b + 128;
  const u16 *pUA2a = gA2a + 128, *pUA2b = gA2b + 128;

  bf16x8 af[4][2], bf0[2][2], bf1[2][2];

#define LOADA(Ab, hm)                                                     \
  _Pragma("unroll") for (int mb = 0; mb < 4; ++mb) {                      \
    const u16* rp_ = (Ab) + (wm * 128 + (hm) * 64 + mb * 16 + l15) * 64;  \
    af[mb][0] = *(const bf16x8*)&rp_[((quad ^ sw7) * 8)];                 \
    af[mb][1] = *(const bf16x8*)&rp_[(((4 + quad) ^ sw7) * 8)];           \
  }
#define LOADB(dst, Bb, hn)                                                \
  _Pragma("unroll") for (int nq = 0; nq < 2; ++nq) {                      \
    const u16* rp_ = (Bb) + (wn * 64 + (hn) * 32 + nq * 16 + l15) * 64;   \
    dst[nq][0] = *(const bf16x8*)&rp_[((quad ^ sw7) * 8)];                \
    dst[nq][1] = *(const bf16x8*)&rp_[(((4 + quad) ^ sw7) * 8)];          \
  }
#define MFMAQ(bfh, hm, hn)                                                \
  _Pragma("unroll") for (int mb = 0; mb < 4; ++mb)                        \
  _Pragma("unroll") for (int nq = 0; nq < 2; ++nq) {                      \
    acc[(hm) * 4 + mb][(hn) * 2 + nq] =                                   \
        __builtin_amdgcn_mfma_f32_16x16x32_bf16(                          \
            af[mb][0], bfh[nq][0], acc[(hm) * 4 + mb][(hn) * 2 + nq], 0,  \
            0, 0);                                                        \
    acc[(hm) * 4 + mb][(hn) * 2 + nq] =                                   \
        __builtin_amdgcn_mfma_f32_16x16x32_bf16(                          \
            af[mb][1], bfh[nq][1], acc[(hm) * 4 + mb][(hn) * 2 + nq], 0,  \
            0, 0);                                                        \
  }

#pragma unroll 2
  for (int t = 0; t < 16; ++t) {
    const u16* Ac = ldsA + (t & 1) * 16384;
    const u16* Bc = ldsB + (t & 1) * 16384;
    const int nb1 = (t + 1) & 1;  // buf for tile t+1
    const int nb2 = t & 1;        // buf for tile t+2
    // ---- phase 0: reads UA_p0 + UB_p0 (12 ds_read_b128), stage UB_p1(t+1)
    LOADA(Ac, 0);
    LOADB(bf0, Bc, 0);
    if (t < 15) {
      STAGEU(pUB1a, pUB1b, ldsB, dB1, nb1);
      pUB1a += 64; pUB1b += 64;
    }
    __builtin_amdgcn_s_barrier();
    asm volatile("s_waitcnt lgkmcnt(0)" ::: "memory");
    __builtin_amdgcn_s_setprio(1);
    MFMAQ(bf0, 0, 0);
    __builtin_amdgcn_s_setprio(0);
    __builtin_amdgcn_s_barrier();
    // ---- phase 1: reads UB_p1, stage UA_p0(t+2) (last read p0, closed)
    LOADB(bf1, Bc, 1);
    if (t < 14) {
      STAGEU(pUA0a, pUA0b, ldsA, dA0, nb2);
      pUA0a += 64; pUA0b += 64;
    }
    __builtin_amdgcn_s_barrier();
    asm volatile("s_waitcnt lgkmcnt(0)" ::: "memory");
    __builtin_amdgcn_s_setprio(1);
    MFMAQ(bf1, 0, 1);
    __builtin_amdgcn_s_setprio(0);
    __builtin_amdgcn_s_barrier();
    // ---- phase 2: reads UA_p2, stage UB_p0(t+2) (last read p0, closed)
    LOADA(Ac, 1);
    if (t < 14) {
      STAGEU(pUB0a, pUB0b, ldsB, dB0, nb2);
      pUB0a += 64; pUB0b += 64;
    }
    __builtin_amdgcn_s_barrier();
    asm volatile("s_waitcnt lgkmcnt(0)" ::: "memory");
    __builtin_amdgcn_s_setprio(1);
    MFMAQ(bf0, 1, 0);
    __builtin_amdgcn_s_setprio(0);
    __builtin_amdgcn_s_barrier();
    // ---- phase 3: regs only, stage UA_p2(t+2) (last read p2, closed)
    if (t < 14) {
      STAGEU(pUA2a, pUA2b, ldsA, dA2, nb2);
      pUA2a += 64; pUA2b += 64;
    }
    __builtin_amdgcn_s_setprio(1);
    MFMAQ(bf1, 1, 1);
    __builtin_amdgcn_s_setprio(0);
    if (t < 14) {
      asm volatile("s_waitcnt vmcnt(6)" ::: "memory");
      __builtin_amdgcn_s_barrier();
    } else if (t == 14) {
      asm volatile("s_waitcnt vmcnt(0)" ::: "memory");
      __builtin_amdgcn_s_barrier();
    }
  }
#undef STAGEU
#undef LOADA
#undef LOADB
#undef MFMAQ

  if (wsel < 2) {
    const float qs = (wsel == 0) ? 0.125f * 1.44269504088896f : 1.0f;
    const int colb = n0 + wn * 64;
    const int h = colb >> 6;
    const float bias0 = bsel[colb + l15];
    const float bias1 = bsel[colb + 16 + l15];
    const float bias2 = bsel[colb + 32 + l15];
    const float bias3 = bsel[colb + 48 + l15];
#pragma unroll
    for (int mb = 0; mb < 8; ++mb)
#pragma unroll
      for (int r = 0; r < 4; ++r) {
        int m = m0 + wm * 128 + mb * 16 + quad * 4 + r;
        int b = m >> 11, s = m & (SS - 1);
        float2 t0 = tab[s * 32 + l15];
        float2 t1 = tab[s * 32 + 16 + l15];
        size_t obase = ((size_t)(b * NHH + h) * SS + s) * HDD;
        float x1 = acc[mb][0][r] + bias0;
        float x2 = acc[mb][2][r] + bias2;
        Osel[obase + l15] = f2bf((x1 * t0.x - x2 * t0.y) * qs);
        Osel[obase + 32 + l15] = f2bf((x2 * t0.x + x1 * t0.y) * qs);
        float y1 = acc[mb][1][r] + bias1;
        float y2 = acc[mb][3][r] + bias3;
        Osel[obase + 16 + l15] = f2bf((y1 * t1.x - y2 * t1.y) * qs);
        Osel[obase + 48 + l15] = f2bf((y2 * t1.x + y1 * t1.y) * qs);
      }
  } else {
#pragma unroll
    for (int nb = 0; nb < 4; ++nb) {
      int col = n0 + wn * 64 + nb * 16 + l15;
      int h = col >> 6, d = col & 63;
      float bias = bsel[col];
#pragma unroll
      for (int mb = 0; mb < 8; ++mb) {
        int m = m0 + wm * 128 + mb * 16 + quad * 4;
        int b = m >> 11, s = m & (SS - 1);
        uint2 w2;
        w2.x = pk_bf16(acc[mb][nb][0] + bias, acc[mb][nb][1] + bias);
        w2.y = pk_bf16(acc[mb][nb][2] + bias, acc[mb][nb][3] + bias);
        *(uint2*)&Osel[((size_t)((b * NHH + h) * HDD + d)) * SS + s] = w2;
      }
    }
  }
}

// ---------------------------------------------------------------------------
// Final projection GEMM v2: 128x128 tile, BK=64, 4 waves, double-buffered
// 64 KB LDS, depth-2 counted prefetch (T3-min + counted vmcnt; m230: 682 TF
// at this tile). Per K-tile: 16 ds_read_b128 -> barrier (closes all reads of
// this buf) -> stage tile t+2 into it -> lgkmcnt(0)+sched_barrier ->
// setprio+32 MFMA -> vmcnt(8) [t+1 landed, t+2's 8 in flight] -> barrier.
// Never vmcnt(0) in-loop (tail: t==14). Same k-sequential accumulate order
// as v1 -> bit-identical output. Grid 256 = 1/CU, bijective XCD swizzle.
// ---------------------------------------------------------------------------
__global__ __launch_bounds__(256) void gemm_out(const u16* __restrict__ X,
                                                const u16* __restrict__ W,
                                                float* __restrict__ Ofp) {
  __shared__ __align__(16) u16 As[2][8192];  // [buf][128*64]
  __shared__ __align__(16) u16 Bs[2][8192];
  const int tid = threadIdx.x;
  const int lane = tid & 63;
  const int wv = __builtin_amdgcn_readfirstlane(tid >> 6);
  const int l15 = lane & 15, quad = lane >> 4;
  const int sw7 = l15 & 7;
  const int wm = wv >> 1, wn = wv & 1;
  const int r8 = lane >> 3, c7 = lane & 7;

  int wg = blockIdx.x;
  int swz = (wg & 7) * 32 + (wg >> 3);  // 256 % 8 == 0: bijective
  const int n0 = (swz & 7) * 128;
  const int m0 = (swz >> 3) * 128;

  const int csw = (c7 ^ r8) * 8;
  const u16* gA = X + (size_t)(m0 + wv * 32 + r8) * HH + csw;
  const u16* gB = W + (size_t)(n0 + wv * 32 + r8) * HH + csw;
  u16* const dA = &As[0][0] + (wv * 32) * 64;
  u16* const dB = &Bs[0][0] + (wv * 32) * 64;

#define STG_O(tile, buf)                                           \
  _Pragma("unroll") for (int u = 0; u < 4; ++u) {                  \
    gload_lds16(gA + (size_t)u * 8 * HH + (tile) * 64,             \
                dA + (buf) * 8192 + u * 512);                      \
    gload_lds16(gB + (size_t)u * 8 * HH + (tile) * 64,             \
                dB + (buf) * 8192 + u * 512);                      \
  }

  floatx4 acc[4][4];
#pragma unroll
  for (int i = 0; i < 4; ++i)
#pragma unroll
    for (int j = 0; j < 4; ++j) acc[i][j] = (floatx4){0.f, 0.f, 0.f, 0.f};

  STG_O(0, 0);
  STG_O(1, 1);
  asm volatile("s_waitcnt vmcnt(8)" ::: "memory");
  __builtin_amdgcn_s_barrier();

  for (int t = 0; t < 16; ++t) {
    const u16* Ac = &As[0][0] + (t & 1) * 8192;
    const u16* Bc = &Bs[0][0] + (t & 1) * 8192;
    bf16x8 af[4][2], bfr[4][2];
#pragma unroll
    for (int mb = 0; mb < 4; ++mb) {
      const u16* rp = Ac + (wm * 64 + mb * 16 + l15) * 64;
      af[mb][0] = *(const bf16x8*)&rp[(quad ^ sw7) * 8];
      af[mb][1] = *(const bf16x8*)&rp[((4 + quad) ^ sw7) * 8];
    }
#pragma unroll
    for (int nb = 0; nb < 4; ++nb) {
      const u16* rp = Bc + (wn * 64 + nb * 16 + l15) * 64;
      bfr[nb][0] = *(const bf16x8*)&rp[(quad ^ sw7) * 8];
      bfr[nb][1] = *(const bf16x8*)&rp[((4 + quad) ^ sw7) * 8];
    }
    __builtin_amdgcn_s_barrier();  // all waves' reads of this buf issued
    if (t < 14) STG_O(t + 2, t & 1);
    asm volatile("s_waitcnt lgkmcnt(0)" ::: "memory");
    __builtin_amdgcn_sched_barrier(0);
    __builtin_amdgcn_s_setprio(1);
#pragma unroll
    for (int mb = 0; mb < 4; ++mb)
#pragma unroll
      for (int nb = 0; nb < 4; ++nb) {
        acc[mb][nb] = __builtin_amdgcn_mfma_f32_16x16x32_bf16(
            af[mb][0], bfr[nb][0], acc[mb][nb], 0, 0, 0);
        acc[mb][nb] = __builtin_amdgcn_mfma_f32_16x16x32_bf16(
            af[mb][1], bfr[nb][1], acc[mb][nb], 0, 0, 0);
      }
    __builtin_amdgcn_s_setprio(0);
    if (t < 14) {
      asm volatile("s_waitcnt vmcnt(8)" ::: "memory");
    } else if (t == 14) {
      asm volatile("s_waitcnt vmcnt(0)" ::: "memory");
    }
    __builtin_amdgcn_s_barrier();
  }
#undef STG_O

#pragma unroll
  for (int mb = 0; mb < 4; ++mb)
#pragma unroll
    for (int r = 0; r < 4; ++r) {
      int m = m0 + wm * 64 + mb * 16 + quad * 4 + r;
#pragma unroll
      for (int nb = 0; nb < 4; ++nb)
        Ofp[(size_t)m * HH + n0 + wn * 64 + nb * 16 + l15] = acc[mb][nb][r];
    }
}

// ---------------------------------------------------------------------------
// Flash attention, key-partitioned quadrant scheme (R4: raw v_exp_f32,
// v_cvt_pk_bf16_f32 asm, uniform-base staging, setprio on MFMA clusters).
// ---------------------------------------------------------------------------
__global__ __launch_bounds__(256, 4) void attn_mfma(const u16* __restrict__ Qg,
                                                    const u16* __restrict__ Kg,
                                                    const u16* __restrict__ Vtg,
                                                    u16* __restrict__ A) {
  __shared__ __align__(16) u16 smem[16384];  // 32 KB
  u16* const Ks0 = smem;
  u16* const Ks1 = smem + 4096;
  u16* const Vs0 = smem + 8192;
  u16* const Vs1 = smem + 12288;
  float* const lpart = (float*)smem;        // [4][32]
  float* const Opart = (float*)smem + 128;  // [2][32][68]

  const int tid = threadIdx.x;
  const int lane = tid & 63;
  const int wv = __builtin_amdgcn_readfirstlane(tid >> 6);
  const int l15 = lane & 15, quad = lane >> 4;
  const int sw7 = l15 & 7;
  const int bh = blockIdx.x, qt = blockIdx.y;
  const size_t hb = (size_t)bh * SS * HDD;  // Q,K [bh][s][d]; Vt [bh][d][s]
  const int kh = wv >> 1;  // key-half
  const int qh = wv & 1;   // qrow-half

  // staging geometry: wave covers segs {wv*2, wv*2+1} of 8 rows each.
  // uniform bases + loop-invariant per-lane offsets (scalar tile advance).
  const int r8 = lane >> 3, c7 = lane & 7;
  const int cs = (c7 ^ r8) * 8;  // XOR-swizzled chunk (u16 offset)
  const u16* const Kt = Kg + hb;
  const u16* const Vt = Vtg + hb;
  const int row0 = (wv * 2 + 0) * 8 + r8;
  const int row1 = (wv * 2 + 1) * 8 + r8;
  const int koff0 = row0 * HDD + cs;
  const int koff1 = row1 * HDD + cs;
  const int voff0 = row0 * SS + cs;
  const int voff1 = row1 * SS + cs;
  u16* const kd0 = smem + (wv * 2 + 0) * 512;  // LDS dst (buf-relative)
  u16* const kd1 = smem + (wv * 2 + 1) * 512;

  // stage Q (64x64) into Ks1 + first K/V tile into buf0
  gload_lds16(Qg + hb + qt * 4096 + koff0, kd0 + 4096);
  gload_lds16(Qg + hb + qt * 4096 + koff1, kd1 + 4096);
  gload_lds16(Kt + koff0, kd0);
  gload_lds16(Kt + koff1, kd1);
  gload_lds16(Vt + voff0, kd0 + 8192);
  gload_lds16(Vt + voff1, kd1 + 8192);
  __syncthreads();

  // Q B-frags (loop-invariant): qrows qh*32 + nb*16 + l15
  bf16x8 qf[2][2];
#pragma unroll
  for (int nb = 0; nb < 2; ++nb)
#pragma unroll
    for (int h2 = 0; h2 < 2; ++h2)
      qf[nb][h2] = *(const bf16x8*)&Ks1[(qh * 32 + nb * 16 + l15) * 64 +
                                        (((h2 * 4 + quad) ^ sw7) * 8)];
  __syncthreads();  // qf reads complete before t=1 staging overwrites Ks1

  float l_acc[2] = {0.f, 0.f};
  floatx4 o[4][2];
#pragma unroll
  for (int dmb = 0; dmb < 4; ++dmb)
#pragma unroll
    for (int nb = 0; nb < 2; ++nb) o[dmb][nb] = (floatx4){0.f, 0.f, 0.f, 0.f};

  // one key-tile compute, statically-addressed buffers
  auto tile_compute = [&](const u16* ks, const u16* vs) {
    // S^T quadrant: keys kh*32+kmb*16+quad*4+r, qrows qh*32+nb*16+l15
    floatx4 st[2][2];
    __builtin_amdgcn_s_setprio(1);
#pragma unroll
    for (int kmb = 0; kmb < 2; ++kmb) {
      int krow = kh * 32 + kmb * 16 + l15;
      bf16x8 ak0 = *(const bf16x8*)&ks[krow * 64 + ((quad ^ sw7) * 8)];
      bf16x8 ak1 = *(const bf16x8*)&ks[krow * 64 + (((4 + quad) ^ sw7) * 8)];
#pragma unroll
      for (int nb = 0; nb < 2; ++nb) {
        floatx4 z = (floatx4){0.f, 0.f, 0.f, 0.f};
        z = __builtin_amdgcn_mfma_f32_16x16x32_bf16(ak0, qf[nb][0], z, 0, 0, 0);
        z = __builtin_amdgcn_mfma_f32_16x16x32_bf16(ak1, qf[nb][1], z, 0, 0, 0);
        st[kmb][nb] = z;
      }
    }
    __builtin_amdgcn_s_setprio(0);

    // exp2 + pack P into MFMA-B layout (permutation trick, in-register).
    // raw v_exp_f32 + raw v_cvt_pk_bf16_f32.
    bf16x8 bp[2];
#pragma unroll
    for (int nb = 0; nb < 2; ++nb) {
      float p00 = __builtin_amdgcn_exp2f(st[0][nb][0]);
      float p01 = __builtin_amdgcn_exp2f(st[0][nb][1]);
      float p02 = __builtin_amdgcn_exp2f(st[0][nb][2]);
      float p03 = __builtin_amdgcn_exp2f(st[0][nb][3]);
      float p10 = __builtin_amdgcn_exp2f(st[1][nb][0]);
      float p11 = __builtin_amdgcn_exp2f(st[1][nb][1]);
      float p12 = __builtin_amdgcn_exp2f(st[1][nb][2]);
      float p13 = __builtin_amdgcn_exp2f(st[1][nb][3]);
      l_acc[nb] += ((p00 + p01) + (p02 + p03)) + ((p10 + p11) + (p12 + p13));
      union { bf16x8 v; unsigned u[4]; } pu;
      pu.u[0] = pk_asm(p00, p01);
      pu.u[1] = pk_asm(p02, p03);
      pu.u[2] = pk_asm(p10, p11);
      pu.u[3] = pk_asm(p12, p13);
      bp[nb] = pu.v;
    }

    // O^T += V^T(perm) . P(perm): A elem j = Vt[d][kh*32+(j>>2)*16+quad*4+(j&3)]
    const int cb0 = kh * 4 + (quad >> 1);
    const int cb1 = cb0 + 2;
    const int sub = (quad & 1) * 4;
    __builtin_amdgcn_s_setprio(1);
#pragma unroll
    for (int dmb = 0; dmb < 4; ++dmb) {
      int vr = (dmb * 16 + l15) * 64;
      union { bf16x8 v; uint2 d2[2]; } au;
      au.d2[0] = *(const uint2*)&vs[vr + ((cb0 ^ sw7) * 8) + sub];
      au.d2[1] = *(const uint2*)&vs[vr + ((cb1 ^ sw7) * 8) + sub];
#pragma unroll
      for (int nb = 0; nb < 2; ++nb)
        o[dmb][nb] = __builtin_amdgcn_mfma_f32_16x16x32_bf16(au.v, bp[nb],
                                                             o[dmb][nb], 0, 0, 0);
    }
    __builtin_amdgcn_s_setprio(0);
  };

  for (int tt = 0; tt < SS / 64; tt += 2) {
    // half 0: prefetch tile tt+1 -> buf1 (tt+1 <= 31 always), compute buf0
    {
      const int k1 = (tt + 1) * 64 * HDD;  // uniform
      const int v1 = (tt + 1) * 64;        // uniform
      gload_lds16(Kt + k1 + koff0, kd0 + 4096);
      gload_lds16(Kt + k1 + koff1, kd1 + 4096);
      gload_lds16(Vt + v1 + voff0, kd0 + 12288);
      gload_lds16(Vt + v1 + voff1, kd1 + 12288);
    }
    tile_compute(Ks0, Vs0);
    __syncthreads();

    // half 1: prefetch tile tt+2 -> buf0 (guarded), compute buf1
    if (tt < SS / 64 - 2) {
      const int k2 = (tt + 2) * 64 * HDD;
      const int v2 = (tt + 2) * 64;
      gload_lds16(Kt + k2 + koff0, kd0);
      gload_lds16(Kt + k2 + koff1, kd1);
      gload_lds16(Vt + v2 + voff0, kd0 + 8192);
      gload_lds16(Vt + v2 + voff1, kd1 + 8192);
    }
    tile_compute(Ks1, Vs1);
    __syncthreads();
  }

  // ---- epilogue: combine key-halves ----
  // l: reduce over quads (16 keys of this wave), publish per-wave partial
#pragma unroll
  for (int nb = 0; nb < 2; ++nb) {
    l_acc[nb] += __shfl_xor(l_acc[nb], 16);
    l_acc[nb] += __shfl_xor(l_acc[nb], 32);
  }
  if (quad == 0) {
    lpart[wv * 32 + l15] = l_acc[0];
    lpart[wv * 32 + 16 + l15] = l_acc[1];
  }
  // O: waves kh==1 publish partial (qrow-major rows of 68 fp32)
  if (kh == 1) {
    float* dst = Opart + qh * (32 * 68);
#pragma unroll
    for (int nb = 0; nb < 2; ++nb)
#pragma unroll
      for (int dmb = 0; dmb < 4; ++dmb)
        *(floatx4*)&dst[(nb * 16 + l15) * 68 + dmb * 16 + quad * 4] =
            o[dmb][nb];
  }
  __syncthreads();
  if (kh == 0) {
    const int b = bh >> 4, h = bh & 15;
    const float* src = Opart + qh * (32 * 68);
    float inv[2];
#pragma unroll
    for (int nb = 0; nb < 2; ++nb)
      inv[nb] = 1.f / (lpart[wv * 32 + nb * 16 + l15] +
                       lpart[(wv + 2) * 32 + nb * 16 + l15]);
#pragma unroll
    for (int nb = 0; nb < 2; ++nb) {
      int s = qt * 64 + qh * 32 + nb * 16 + l15;
#pragma unroll
      for (int dmb = 0; dmb < 4; ++dmb) {
        floatx4 part =
            *(const floatx4*)&src[(nb * 16 + l15) * 68 + dmb * 16 + quad * 4];
        floatx4 tot = (o[dmb][nb] + part) * inv[nb];
        uint2 w2;
        w2.x = pk_asm(tot[0], tot[1]);
        w2.y = pk_asm(tot[2], tot[3]);
        *(uint2*)&A[((size_t)(b * SS + s) * HH) + h * HDD + dmb * 16 +
                    quad * 4] = w2;
      }
    }
  }
}

// ---------------------------------------------------------------------------
extern "C" void kernel_launch(void* const* d_in, const int* in_sizes, int n_in,
                              void* d_out, int out_size, void* d_ws,
                              size_t ws_size, hipStream_t stream) {
  const float* hs = (const float*)d_in[0];
  const int* pos = (const int*)d_in[1];
  const float* Wq = (const float*)d_in[2];
  const float* bq = (const float*)d_in[3];
  const float* Wk = (const float*)d_in[4];
  const float* bk = (const float*)d_in[5];
  const float* Wv = (const float*)d_in[6];
  const float* bv = (const float*)d_in[7];
  const float* Wo = (const float*)d_in[8];
  float* out = (float*)d_out;

  u16* hs_b = (u16*)d_ws;      // 4M
  u16* wq_b = hs_b + 4194304;  // 1M each
  u16* wk_b = wq_b + 1048576;
  u16* wv_b = wk_b + 1048576;
  u16* wo_b = wv_b + 1048576;
  u16* Qb = wo_b + 1048576;    // 4M each
  u16* Kb = Qb + 4194304;
  u16* Vtb = Kb + 4194304;     // transposed V [bh][d][s]
  u16* Ab = Vtb + 4194304;
  float2* tab = (float2*)(Ab + 4194304);  // [2048][32] cos/sin

  hipLaunchKernelGGL(convert_bf, dim3(8448), dim3(256), 0, stream, hs, Wq, Wk,
                     Wv, Wo, pos, hs_b, wq_b, wk_b, wv_b, wo_b, tab);
  hipLaunchKernelGGL(mfma_gemm_qkv, dim3(192), dim3(512), 0, stream, hs_b,
                     wq_b, wk_b, wv_b, bq, bk, bv, tab, Qb, Kb, Vtb);
  hipLaunchKernelGGL(attn_mfma, dim3(32, 32), dim3(256), 0, stream, Qb, Kb,
                     Vtb, Ab);
  hipLaunchKernelGGL(gemm_out, dim3(256), dim3(256), 0, stream, Ab, wo_b,
                     out);
}